// Round 4
// baseline (385.659 us; speedup 1.0000x reference)
//
#include <hip/hip_runtime.h>
#include <math.h>

#define N_NODES 20
#define IN_DIM  9
#define HID     128
#define K_NBR   5
#define EPS     1e-5f
#define IPB     2          // items (waves) per 128-thread block

// ---- per-item LDS slice (bytes), regions with disjoint lifetimes alias at 0 ----
// phase A: xs (180 f32 = 720B @0) + adjx (20x16 bf16 = 640B @736)
// phase B: hrm (20 rows x 136 bf16 = 5440B @0)   h row-major, A-operand for t=h@W2
// phase C: tT  (128 cols x 24 bf16 = 6144B @0)   t transposed, B-operand for adj@t
// guard  : 16B zeros @6144 (col127/q3 B-frag overread target; never clobbered)
// resid1 : mt=1 residual rows 16-19, [nt][ln15] u32x2 = 1024B @6160 (scatter->final)
// mt=0 residual stays in REGISTERS (hU01/hU23).
// SEQUENTIAL-mt: one f32x4 acc[8] (32 regs) instead of acc[2][8] (64) — mt=0 and
// mt=1 passes run back-to-back, B-fragments re-read per pass (L2-hit, laundered
// against CSE). Unified reg target <=128 -> 4 waves/SIMD (vs 148 -> 3 before).
#define ADJX_OFF  736
#define RES1_OFF  6160
#define SLICE     7184
#define HTSTR     24       // tT row-slots per col (multiple of 8 -> b128-aligned reads)
#define HRSTR     136      // hrm row stride (272B: 16B-mult, 4 mod 32 banks -> 2-way free)

typedef __attribute__((ext_vector_type(8))) short short8;   // 8 bf16 (4 VGPRs)
typedef __attribute__((ext_vector_type(4))) float f32x4;    // MFMA C/D frag
typedef __attribute__((ext_vector_type(2))) float f32x2;    // v_pk_*_f32 carrier
typedef __attribute__((ext_vector_type(2))) unsigned int u32x2;
typedef __attribute__((ext_vector_type(4))) unsigned int u32x4;

#define WB() __builtin_amdgcn_wave_barrier()

__device__ __forceinline__ unsigned short f2bf(float f) {
    unsigned u = __builtin_bit_cast(unsigned, f);
    u += 0x7fffu + ((u >> 16) & 1u);          // RNE
    return (unsigned short)(u >> 16);
}
#if __has_builtin(__builtin_amdgcn_cvt_pk_bf16_f32)
typedef __attribute__((ext_vector_type(2))) __bf16 bf16x2;
__device__ __forceinline__ unsigned cvtpk(float a, float b) {   // low=bf16(a), hi=bf16(b)
    bf16x2 r = __builtin_amdgcn_cvt_pk_bf16_f32(a, b);
    return __builtin_bit_cast(unsigned, r);
}
#else
__device__ __forceinline__ unsigned cvtpk(float a, float b) {
    return (unsigned)f2bf(a) | ((unsigned)f2bf(b) << 16);
}
#endif
// unpack a bf16 pair (one u32) to two floats: lo = bits<<16, hi = bits&0xffff0000
__device__ __forceinline__ f32x2 unpk(unsigned u) {
    return (f32x2){ __builtin_bit_cast(float, u << 16),
                    __builtin_bit_cast(float, u & 0xffff0000u) };
}
// tanh-form GELU (|err| <~1e-3): x*u/(u+1), u=e^{2*0.79788456*(x+0.044715x^3)}
__device__ __forceinline__ float gelu_fast(float x) {
    float x2 = x * x;
    float y  = x * fmaf(x2, 0.07135806592f, 1.5957691216f);
    float u  = __expf(fminf(y, 60.0f));
    return x * u * __builtin_amdgcn_rcpf(u + 1.0f);
}
// packed 2-element gelu: polynomial in v_pk_*, exp/rcp scalar (no pk transcendentals)
__device__ __forceinline__ f32x2 gelu2(f32x2 x) {
    f32x2 x2 = x * x;
    f32x2 y  = x * (x2 * 0.07135806592f + 1.5957691216f);
    f32x2 u  = { __expf(fminf(y.x, 60.0f)), __expf(fminf(y.y, 60.0f)) };
    f32x2 n  = x * u;
    f32x2 d  = u + 1.0f;
    return (f32x2){ n.x * __builtin_amdgcn_rcpf(d.x), n.y * __builtin_amdgcn_rcpf(d.y) };
}
__device__ __forceinline__ f32x2 shfl2(f32x2 v, int m) {
    return (f32x2){ __shfl_xor(v.x, m), __shfl_xor(v.y, m) };
}

__device__ __forceinline__ f32x4 mfma16(short8 a, short8 b, f32x4 c) {
    return __builtin_amdgcn_mfma_f32_16x16x32_bf16(a, b, c, 0, 0, 0);
}

// LN stats over acc[8] (one mt half): packed mean/rstd for reg-pairs (0,1) and (2,3)
#define LN_STATS(ACC, MEAN01, MEAN23, RSTD01, RSTD23)                              \
  { f32x2 s01={0,0}, s23={0,0}, t01={0,0}, t23={0,0};                              \
    _Pragma("unroll")                                                              \
    for (int nt_ = 0; nt_ < 8; ++nt_) {                                            \
      f32x2 v01_ = {ACC[nt_][0], ACC[nt_][1]};                                     \
      f32x2 v23_ = {ACC[nt_][2], ACC[nt_][3]};                                     \
      s01 += v01_; s23 += v23_; t01 += v01_*v01_; t23 += v23_*v23_; }              \
    _Pragma("unroll")                                                              \
    for (int m_ = 1; m_ < 16; m_ <<= 1) {                                          \
      s01 += shfl2(s01,m_); s23 += shfl2(s23,m_);                                  \
      t01 += shfl2(t01,m_); t23 += shfl2(t23,m_); }                                \
    MEAN01 = s01 * (1.f/HID); MEAN23 = s23 * (1.f/HID);                            \
    f32x2 va_ = t01 * (1.f/HID) - MEAN01*MEAN01;                                   \
    f32x2 vb_ = t23 * (1.f/HID) - MEAN23*MEAN23;                                   \
    RSTD01 = (f32x2){ rsqrtf(fmaxf(va_.x,0.f)+EPS), rsqrtf(fmaxf(va_.y,0.f)+EPS) };\
    RSTD23 = (f32x2){ rsqrtf(fmaxf(vb_.x,0.f)+EPS), rsqrtf(fmaxf(vb_.y,0.f)+EPS) };}

// ===== single prep kernel, fully parallel =====
__global__ void prep_all(const float* __restrict__ w_embed, const float* __restrict__ b_embed,
                         const float* __restrict__ w1, const float* __restrict__ b1,
                         const float* __restrict__ w2,
                         unsigned short* __restrict__ wswM1, unsigned short* __restrict__ wsw2,
                         float* __restrict__ c1f) {
    int tid = blockIdx.x * 256 + threadIdx.x;          // 33280 total -> 130 blocks
    if (tid < 16384) {
        int oid = tid >> 2, sub = tid & 3;
        int j = oid & 7, lane = (oid >> 3) & 63, nt = (oid >> 9) & 7;
        int k = (lane >> 4) * 8 + j;
        int n = nt * 16 + (lane & 15);
        float acc = 0.f;
        if (k < IN_DIM) {
            #pragma unroll 8
            for (int c = sub * 32; c < sub * 32 + 32; ++c)
                acc = fmaf(w_embed[k*HID + c], w1[c*HID + n], acc);
        }
        acc += __shfl_xor(acc, 1);
        acc += __shfl_xor(acc, 2);
        if (sub == 0) wswM1[oid] = (k < IN_DIM) ? f2bf(acc) : (unsigned short)0;
    } else if (tid < 16896) {
        int t2 = tid - 16384;
        int n = t2 >> 2, sub = t2 & 3;
        float cb = 0.f;
        #pragma unroll 8
        for (int c = sub * 32; c < sub * 32 + 32; ++c)
            cb = fmaf(b_embed[c], w1[c*HID + n], cb);
        cb += __shfl_xor(cb, 1);
        cb += __shfl_xor(cb, 2);
        if (sub == 0) c1f[n] = 5.0f * cb + b1[n];
    } else if (tid < 33280) {
        int i2 = tid - 16896;
        int j = i2 & 7, lane = (i2 >> 3) & 63, nt = (i2 >> 9) & 7, ks = (i2 >> 12) & 3;
        int k = ks * 32 + (lane >> 4) * 8 + j;
        int n = nt * 16 + (lane & 15);
        wsw2[i2] = f2bf(w2[k*HID + n]);
    }
}

// ===== main =====
__global__ __launch_bounds__(128, 4) void hbond_main(
    const float* __restrict__ x_in,
    const float* __restrict__ c1f, const float* __restrict__ b2,
    const float* __restrict__ g1, const float* __restrict__ be1,
    const float* __restrict__ g2, const float* __restrict__ be2,
    const unsigned short* __restrict__ wswM1, const unsigned short* __restrict__ wsw2,
    float* __restrict__ out, int nItems)
{
    __shared__ __align__(16) unsigned char smem[IPB * SLICE];

    const int l  = threadIdx.x & 63;
    const int wv = threadIdx.x >> 6;
    const int item = blockIdx.x * IPB + wv;
    if (item >= nItems) return;               // wave-uniform; no cross-wave barriers

    unsigned char* slice = smem + wv * SLICE;
    float*          xs   = (float*)(slice);                    // phase A
    unsigned short* adjx = (unsigned short*)(slice + ADJX_OFF);// phase A
    unsigned short* hrm  = (unsigned short*)(slice);           // phase B (aliases A)
    unsigned short* tT   = (unsigned short*)(slice);           // phase C (aliases B)
    unsigned*       resid1 = (unsigned*)(slice + RES1_OFF);    // mt=1 residual

    const int ln15 = l & 15, q = l >> 4;
    const float* xb = x_in + (size_t)item * (N_NODES * IN_DIM);

    // guard for tT col127/q3 overread (bytes 6144..6160)
    if (l == 0) *(u32x4*)(slice + HTSTR * HID * 2) = (u32x4){0,0,0,0};

    // ---- stage x: 180 floats ----
    if (l < 45) ((float4*)xs)[l] = ((const float4*)xb)[l];
    WB();

    // ---- KNN: lane r = row r (r<20); bit-safe d2; tie -> lower index ----
    unsigned nbrp = 0;                        // 5 x 5-bit neighbor indices
    {
        const int rsel = (l < N_NODES) ? l : 0;
        const float px = xs[rsel*IN_DIM+6], py = xs[rsel*IN_DIM+7], pz = xs[rsel*IN_DIM+8];
        float d2[N_NODES];
        #pragma unroll
        for (int j = 0; j < N_NODES; ++j) {
            float dx = __fsub_rn(px, __shfl(px, j));
            float dy = __fsub_rn(py, __shfl(py, j));
            float dz = __fsub_rn(pz, __shfl(pz, j));
            d2[j] = __fadd_rn(__fadd_rn(__fmul_rn(dx,dx), __fmul_rn(dy,dy)), __fmul_rn(dz,dz));
        }
        unsigned used = 0u;
        #pragma unroll
        for (int k = 0; k < K_NBR; ++k) {
            float best = INFINITY; int bi = 0;
            #pragma unroll
            for (int j = 0; j < N_NODES; ++j) {
                bool take = (!((used >> j) & 1u)) && (d2[j] < best);
                best = take ? d2[j] : best;
                bi   = take ? j     : bi;
            }
            used |= (1u << bi);
            nbrp |= (unsigned)bi << (5*k);
        }
    }

    // ---- adjacency bitmask + bf16 A-fragments (k=q*8+j; bits >=20 always 0) ----
    unsigned amask = 0;
    #pragma unroll
    for (int j = 0; j < K_NBR; ++j) amask |= 1u << ((nbrp >> (5*j)) & 31);
    const unsigned am0 = (unsigned)__shfl((int)amask, ln15);
    const unsigned am1 = (unsigned)__shfl((int)amask, ln15 + 16);
    short8 adjf0, adjf1;
    #pragma unroll
    for (int j = 0; j < 8; ++j) {
        adjf0[j] = (short)(((am0 >> (q*8 + j)) & 1u) ? 0x3F80 : 0);
        adjf1[j] = (short)(((am1 >> (q*8 + j)) & 1u) ? 0x3F80 : 0);
    }

    // ---- agg1 on raw x (fp32 exact, packed sums) ----
    if (l < N_NODES) {
        f32x2 s01 = {0,0}, s23 = {0,0}, s45 = {0,0}, s67 = {0,0};
        float s8 = 0.f;
        #pragma unroll
        for (int j = 0; j < K_NBR; ++j) {
            const int b0 = ((nbrp >> (5*j)) & 31) * IN_DIM;
            s01 += (f32x2){xs[b0+0], xs[b0+1]};
            s23 += (f32x2){xs[b0+2], xs[b0+3]};
            s45 += (f32x2){xs[b0+4], xs[b0+5]};
            s67 += (f32x2){xs[b0+6], xs[b0+7]};
            s8  += xs[b0+8];
        }
        u32x4 p0 = { cvtpk(s01.x,s01.y), cvtpk(s23.x,s23.y), cvtpk(s45.x,s45.y), cvtpk(s67.x,s67.y) };
        u32x4 p1 = { cvtpk(s8,0.f), 0, 0, 0 };
        *(u32x4*)&adjx[l*16 + 0] = p0;
        *(u32x4*)&adjx[l*16 + 8] = p1;
    }
    WB();

    f32x4 acc[8];                      // single mt half at a time (32 regs)
    const int rlo = ln15, rhi = (ln15 + 16 > 19) ? 19 : ln15 + 16;  // clamp garbage rows

    // A-fragments for GEMM1, both row-halves, preloaded before hrm overwrites adjx
    const short8 a0g = *(const short8*)&adjx[rlo*16 + (q & 1)*8];
    const short8 a1g = *(const short8*)&adjx[rhi*16 + (q & 1)*8];

    unsigned hU01[8], hU23[8];         // mt=0 residual (rows 0-15), lives to final

    // ---- GEMM1 mt=0: y1 rows 0-15 ----
    #pragma unroll
    for (int nt = 0; nt < 8; ++nt) {
        const float bv = c1f[ln15 + 16*nt];
        acc[nt] = mfma16(a0g, *(const short8*)&wswM1[nt*512 + l*8],
                         (f32x4){bv, bv, bv, bv});
    }
    // ---- LN1 + GELU mt=0 -> hU regs ----
    {
        f32x2 mean01, mean23, rstd01, rstd23;
        LN_STATS(acc, mean01, mean23, rstd01, rstd23);
        #pragma unroll
        for (int nt = 0; nt < 8; ++nt) {
            const int col = ln15 + 16*nt;
            const float gv = g1[col], bv = be1[col];
            f32x2 v01 = {acc[nt][0], acc[nt][1]};
            f32x2 v23 = {acc[nt][2], acc[nt][3]};
            f32x2 h01 = gelu2((v01 - mean01) * rstd01 * gv + bv);
            f32x2 h23 = gelu2((v23 - mean23) * rstd23 * gv + bv);
            hU01[nt] = cvtpk(h01.x, h01.y);
            hU23[nt] = cvtpk(h23.x, h23.y);
        }
    }

    // ---- GEMM1 mt=1: y1 rows 16-19 (B reloaded; laundered index blocks CSE) ----
    {
        int l8b = l * 8;
        asm volatile("" : "+v"(l8b));          // force reload of wswM1 frags
        #pragma unroll
        for (int nt = 0; nt < 8; ++nt) {
            const float bv = c1f[ln15 + 16*nt];
            acc[nt] = mfma16(a1g, *(const short8*)&wswM1[nt*512 + l8b],
                             (f32x4){bv, bv, bv, bv});
        }
    }
    WB();   // all adjx/xs consumption done (a0g/a1g consumed by MFMA)

    // ---- scatter mt=0 h rows 0-15 into hrm (overlaps mt=1 LN VALU below) ----
    #pragma unroll
    for (int nt = 0; nt < 8; ++nt) {
        const int col = ln15 + 16*nt;
        const unsigned u01 = hU01[nt], u23 = hU23[nt];
        hrm[(q*4+0)*HRSTR + col] = (unsigned short)u01;
        hrm[(q*4+1)*HRSTR + col] = (unsigned short)(u01 >> 16);
        hrm[(q*4+2)*HRSTR + col] = (unsigned short)u23;
        hrm[(q*4+3)*HRSTR + col] = (unsigned short)(u23 >> 16);
    }

    // ---- LN1 + GELU mt=1 -> scatter rows 16-19 + resid1 (regs die here) ----
    {
        f32x2 mean01, mean23, rstd01, rstd23;
        LN_STATS(acc, mean01, mean23, rstd01, rstd23);
        #pragma unroll
        for (int nt = 0; nt < 8; ++nt) {
            const int col = ln15 + 16*nt;
            const float gv = g1[col], bv = be1[col];
            f32x2 v01 = {acc[nt][0], acc[nt][1]};
            f32x2 v23 = {acc[nt][2], acc[nt][3]};
            f32x2 h01 = gelu2((v01 - mean01) * rstd01 * gv + bv);
            f32x2 h23 = gelu2((v23 - mean23) * rstd23 * gv + bv);
            const unsigned v01u = cvtpk(h01.x, h01.y);
            const unsigned v23u = cvtpk(h23.x, h23.y);
            if (q == 0) {
                hrm[16*HRSTR + col] = (unsigned short)v01u;
                hrm[17*HRSTR + col] = (unsigned short)(v01u >> 16);
                hrm[18*HRSTR + col] = (unsigned short)v23u;
                hrm[19*HRSTR + col] = (unsigned short)(v23u >> 16);
                *(u32x2*)&resid1[(nt*16 + ln15)*2] = (u32x2){v01u, v23u};
            }
        }
    }
    WB();

    // ---- GEMM2': t = h @ W2, sequential mt. Preload mt=1 A-frags (rows 16-19)
    //      so tT stores (aliasing hrm) can proceed after the mt=0 pass. ----
    short8 a1f[4];
    #pragma unroll
    for (int ks = 0; ks < 4; ++ks)
        a1f[ks] = *(const short8*)&hrm[rhi*HRSTR + ks*32 + q*8];

    // pass mt=0 (rows 0-15)
    #pragma unroll
    for (int nt = 0; nt < 8; ++nt) acc[nt] = (f32x4){0,0,0,0};
    #pragma unroll
    for (int ks = 0; ks < 4; ++ks) {
        const short8 a0k = *(const short8*)&hrm[rlo*HRSTR + ks*32 + q*8];
        #pragma unroll
        for (int nt = 0; nt < 8; ++nt)
            acc[nt] = mfma16(a0k, *(const short8*)&wsw2[(ks*8 + nt)*512 + l*8], acc[nt]);
    }
    WB();   // all hrm reads issued/consumed; tT may overwrite

    // store tT mt=0 rows (q*4 .. q*4+3)
    #pragma unroll
    for (int nt = 0; nt < 8; ++nt) {
        const int col = ln15 + 16*nt;
        u32x2 w0 = { cvtpk(acc[nt][0], acc[nt][1]), cvtpk(acc[nt][2], acc[nt][3]) };
        *(u32x2*)&tT[col*HTSTR + q*4] = w0;
    }

    // pass mt=1 (rows 16-19; laundered index blocks CSE of wsw2 frags)
    {
        int l8c = l * 8;
        asm volatile("" : "+v"(l8c));
        #pragma unroll
        for (int nt = 0; nt < 8; ++nt) acc[nt] = (f32x4){0,0,0,0};
        #pragma unroll
        for (int ks = 0; ks < 4; ++ks) {
            #pragma unroll
            for (int nt = 0; nt < 8; ++nt)
                acc[nt] = mfma16(a1f[ks], *(const short8*)&wsw2[(ks*8 + nt)*512 + l8c], acc[nt]);
        }
    }
    #pragma unroll
    for (int nt = 0; nt < 8; ++nt) {
        const int col = ln15 + 16*nt;
        if (q == 0) {
            u32x2 w1v = { cvtpk(acc[nt][0], acc[nt][1]), cvtpk(acc[nt][2], acc[nt][3]) };
            *(u32x2*)&tT[col*HTSTR + 16] = w1v;
        }
    }
    // zero row-slots 20..23 (stale bytes can encode Inf/NaN; 0*Inf = NaN in MFMA)
    *(u32x2*)&tT[l*HTSTR + 20]        = (u32x2){0,0};
    *(u32x2*)&tT[(l + 64)*HTSTR + 20] = (u32x2){0,0};
    WB();

    // ---- y2 = adj @ t + b2, LN2, final — mt=1 first (carry rmax1/rmin1) ----
    float rmax1[8], rmin1[8];
    {
        #pragma unroll
        for (int nt = 0; nt < 8; ++nt) {
            const float bv = b2[ln15 + 16*nt];
            acc[nt] = mfma16(adjf1, *(const short8*)&tT[(ln15 + 16*nt)*HTSTR + q*8],
                             (f32x4){bv, bv, bv, bv});
        }
        f32x2 mean01, mean23, rstd01, rstd23;
        LN_STATS(acc, mean01, mean23, rstd01, rstd23);
        #pragma unroll
        for (int nt = 0; nt < 8; ++nt) {
            const int col = ln15 + 16*nt;
            const float gv = g2[col], bv = be2[col];
            f32x2 z01 = ((f32x2){acc[nt][0], acc[nt][1]} - mean01) * rstd01 * gv + bv;
            f32x2 z23 = ((f32x2){acc[nt][2], acc[nt][3]} - mean23) * rstd23 * gv + bv;
            const u32x2 hx = *(const u32x2*)&resid1[(nt*16 + ln15)*2];
            f32x2 w01 = z01 + unpk(hx.x);
            f32x2 w23 = z23 + unpk(hx.y);
            const float mx = fmaxf(fmaxf(w01.x, w01.y), fmaxf(w23.x, w23.y));
            const float mn = fminf(fminf(w01.x, w01.y), fminf(w23.x, w23.y));
            rmax1[nt] = (q == 0) ? mx : -INFINITY;
            rmin1[nt] = (q == 0) ? mn :  INFINITY;
        }
    }
    // mt=0 pass (laundered index blocks CSE of tT frags)
    {
        int q8b = q * 8;
        asm volatile("" : "+v"(q8b));
        #pragma unroll
        for (int nt = 0; nt < 8; ++nt) {
            const float bv = b2[ln15 + 16*nt];
            acc[nt] = mfma16(adjf0, *(const short8*)&tT[(ln15 + 16*nt)*HTSTR + q8b],
                             (f32x4){bv, bv, bv, bv});
        }
        f32x2 mean01, mean23, rstd01, rstd23;
        LN_STATS(acc, mean01, mean23, rstd01, rstd23);
        // fused LN2-apply + residual(regs) + minmax + gelu + store
        // gelu unimodal: max over rows = max(gelu(rmin), gelu(rmax))
        #pragma unroll
        for (int nt = 0; nt < 8; ++nt) {
            const int col = ln15 + 16*nt;
            const float gv = g2[col], bv = be2[col];
            f32x2 y01 = ((f32x2){acc[nt][0], acc[nt][1]} - mean01) * rstd01 * gv + bv;
            f32x2 y23 = ((f32x2){acc[nt][2], acc[nt][3]} - mean23) * rstd23 * gv + bv;
            f32x2 r01 = y01 + unpk(hU01[nt]);
            f32x2 r23 = y23 + unpk(hU23[nt]);
            float rmax = fmaxf(fmaxf(fmaxf(r01.x, r01.y), fmaxf(r23.x, r23.y)), rmax1[nt]);
            float rmin = fminf(fminf(fminf(r01.x, r01.y), fminf(r23.x, r23.y)), rmin1[nt]);
            rmax = fmaxf(rmax, __shfl_xor(rmax, 16)); rmin = fminf(rmin, __shfl_xor(rmin, 16));
            rmax = fmaxf(rmax, __shfl_xor(rmax, 32)); rmin = fminf(rmin, __shfl_xor(rmin, 32));
            const float m0 = fmaxf(gelu_fast(rmax), gelu_fast(rmin));
            if (l < 16) out[(size_t)item*HID + 16*nt + l] = m0;
        }
    }
}

extern "C" void kernel_launch(void* const* d_in, const int* in_sizes, int n_in,
                              void* d_out, int out_size, void* d_ws, size_t ws_size,
                              hipStream_t stream) {
    (void)n_in; (void)out_size; (void)ws_size;
    const float* x       = (const float*)d_in[0];
    const float* w_embed = (const float*)d_in[1];
    const float* b_embed = (const float*)d_in[2];
    const float* w1      = (const float*)d_in[3];
    const float* b1      = (const float*)d_in[4];
    const float* w2      = (const float*)d_in[5];
    const float* b2      = (const float*)d_in[6];
    const float* g1      = (const float*)d_in[7];
    const float* be1     = (const float*)d_in[8];
    const float* g2      = (const float*)d_in[9];
    const float* be2     = (const float*)d_in[10];
    float* out = (float*)d_out;

    // ws layout: [c1f 512B][wswM1 8192B][wsw2 32768B]
    unsigned char* ws = (unsigned char*)d_ws;
    float* c1f            = (float*)(ws + 0);
    unsigned short* wswM1 = (unsigned short*)(ws + 512);
    unsigned short* wsw2  = (unsigned short*)(ws + 512 + 8192);

    const int nItems  = in_sizes[0] / (N_NODES * IN_DIM);
    const int nBlocks = (nItems + IPB - 1) / IPB;

    prep_all<<<dim3(130), dim3(256), 0, stream>>>(w_embed, b_embed, w1, b1, w2,
                                                  wswM1, wsw2, c1f);
    hbond_main<<<dim3(nBlocks), dim3(128), 0, stream>>>(
        x, c1f, b2, g1, be1, g2, be2, wswM1, wsw2, out, nItems);
}

// Round 5
// 288.629 us; speedup vs baseline: 1.3362x; 1.3362x over previous
//
#include <hip/hip_runtime.h>
#include <math.h>

#define N_NODES 20
#define IN_DIM  9
#define HID     128
#define K_NBR   5
#define EPS     1e-5f
#define IPB     2          // items (waves) per 128-thread block

// ---- per-item LDS slice (bytes), regions with disjoint lifetimes alias at 0 ----
// phase A: xs (180 f32 = 720B @0) + adjx (20x16 bf16 = 640B @736)
// phase B: hrm (20 rows x 136 bf16 = 5440B @0)   h row-major, A-operand for t=h@W2
// phase C: tT  (128 cols x 24 bf16 = 6144B @0)   t transposed, B-operand for adj@t
// guard  : 16B zeros @6144 (col127/q3 B-frag overread target; never clobbered)
// resid1 : mt=1 residual rows 16-19, [nt][ln15] u32x2 = 1024B @6160 (scatter->final)
// mt=0 residual stays in REGISTERS (hU01/hU23). 64-AGPR dual-mt accumulator kept:
// natural unified usage ~148 regs -> 3 waves/SIMD is the ceiling (bound-4 spills,
// measured rounds 2 & 4). This round: DPP butterflies (DS->VALU) to cut stalls.
#define ADJX_OFF  736
#define RES1_OFF  6160
#define SLICE     7184
#define HTSTR     24       // tT row-slots per col (multiple of 8 -> b128-aligned reads)
#define HRSTR     136      // hrm row stride (272B: 16B-mult, 4 mod 32 banks -> 2-way free)

typedef __attribute__((ext_vector_type(8))) short short8;   // 8 bf16 (4 VGPRs)
typedef __attribute__((ext_vector_type(4))) float f32x4;    // MFMA C/D frag
typedef __attribute__((ext_vector_type(2))) float f32x2;    // v_pk_*_f32 carrier
typedef __attribute__((ext_vector_type(2))) unsigned int u32x2;
typedef __attribute__((ext_vector_type(4))) unsigned int u32x4;

#define WB() __builtin_amdgcn_wave_barrier()

__device__ __forceinline__ unsigned short f2bf(float f) {
    unsigned u = __builtin_bit_cast(unsigned, f);
    u += 0x7fffu + ((u >> 16) & 1u);          // RNE
    return (unsigned short)(u >> 16);
}
#if __has_builtin(__builtin_amdgcn_cvt_pk_bf16_f32)
typedef __attribute__((ext_vector_type(2))) __bf16 bf16x2;
__device__ __forceinline__ unsigned cvtpk(float a, float b) {   // low=bf16(a), hi=bf16(b)
    bf16x2 r = __builtin_amdgcn_cvt_pk_bf16_f32(a, b);
    return __builtin_bit_cast(unsigned, r);
}
#else
__device__ __forceinline__ unsigned cvtpk(float a, float b) {
    return (unsigned)f2bf(a) | ((unsigned)f2bf(b) << 16);
}
#endif
// unpack a bf16 pair (one u32) to two floats: lo = bits<<16, hi = bits&0xffff0000
__device__ __forceinline__ f32x2 unpk(unsigned u) {
    return (f32x2){ __builtin_bit_cast(float, u << 16),
                    __builtin_bit_cast(float, u & 0xffff0000u) };
}
// tanh-form GELU (|err| <~1e-3): x*u/(u+1), u=e^{2*0.79788456*(x+0.044715x^3)}
__device__ __forceinline__ float gelu_fast(float x) {
    float x2 = x * x;
    float y  = x * fmaf(x2, 0.07135806592f, 1.5957691216f);
    float u  = __expf(fminf(y, 60.0f));
    return x * u * __builtin_amdgcn_rcpf(u + 1.0f);
}
// packed 2-element gelu: polynomial in v_pk_*, exp/rcp scalar (no pk transcendentals)
__device__ __forceinline__ f32x2 gelu2(f32x2 x) {
    f32x2 x2 = x * x;
    f32x2 y  = x * (x2 * 0.07135806592f + 1.5957691216f);
    f32x2 u  = { __expf(fminf(y.x, 60.0f)), __expf(fminf(y.y, 60.0f)) };
    f32x2 n  = x * u;
    f32x2 d  = u + 1.0f;
    return (f32x2){ n.x * __builtin_amdgcn_rcpf(d.x), n.y * __builtin_amdgcn_rcpf(d.y) };
}
__device__ __forceinline__ f32x2 shfl2(f32x2 v, int m) {
    return (f32x2){ __shfl_xor(v.x, m), __shfl_xor(v.y, m) };
}

// ---- DPP cross-lane (pure VALU, no DS pipe / lgkmcnt) ----
// 16-lane all-reduce via xor-levels {1,2,7,8}: a GF(2) basis of [0,16)
// (7 = 1^2^4 so 4 is in the span). All four exist as DPP ctrls:
//   xor1 = quad_perm[1,0,3,2] (0xB1), xor2 = quad_perm[2,3,0,1] (0x4E),
//   xor7 = row_half_mirror (0x141),   xor8 = row_ror:8 (0x128).
template<int CTRL>
__device__ __forceinline__ float dppf(float v) {
    int i = __builtin_bit_cast(int, v);
    return __builtin_bit_cast(float,
        __builtin_amdgcn_update_dpp(i, i, CTRL, 0xF, 0xF, false));
}
template<int CTRL>
__device__ __forceinline__ f32x2 dpp2(f32x2 v) {
    return (f32x2){ dppf<CTRL>(v.x), dppf<CTRL>(v.y) };
}
#define DPP_RED16(V) { V += dpp2<0xB1>(V); V += dpp2<0x4E>(V); \
                       V += dpp2<0x141>(V); V += dpp2<0x128>(V); }

__device__ __forceinline__ f32x4 mfma16(short8 a, short8 b, f32x4 c) {
    return __builtin_amdgcn_mfma_f32_16x16x32_bf16(a, b, c, 0, 0, 0);
}

// ===== single prep kernel, fully parallel =====
__global__ void prep_all(const float* __restrict__ w_embed, const float* __restrict__ b_embed,
                         const float* __restrict__ w1, const float* __restrict__ b1,
                         const float* __restrict__ w2,
                         unsigned short* __restrict__ wswM1, unsigned short* __restrict__ wsw2,
                         float* __restrict__ c1f) {
    int tid = blockIdx.x * 256 + threadIdx.x;          // 33280 total -> 130 blocks
    if (tid < 16384) {
        int oid = tid >> 2, sub = tid & 3;
        int j = oid & 7, lane = (oid >> 3) & 63, nt = (oid >> 9) & 7;
        int k = (lane >> 4) * 8 + j;
        int n = nt * 16 + (lane & 15);
        float acc = 0.f;
        if (k < IN_DIM) {
            #pragma unroll 8
            for (int c = sub * 32; c < sub * 32 + 32; ++c)
                acc = fmaf(w_embed[k*HID + c], w1[c*HID + n], acc);
        }
        acc += __shfl_xor(acc, 1);
        acc += __shfl_xor(acc, 2);
        if (sub == 0) wswM1[oid] = (k < IN_DIM) ? f2bf(acc) : (unsigned short)0;
    } else if (tid < 16896) {
        int t2 = tid - 16384;
        int n = t2 >> 2, sub = t2 & 3;
        float cb = 0.f;
        #pragma unroll 8
        for (int c = sub * 32; c < sub * 32 + 32; ++c)
            cb = fmaf(b_embed[c], w1[c*HID + n], cb);
        cb += __shfl_xor(cb, 1);
        cb += __shfl_xor(cb, 2);
        if (sub == 0) c1f[n] = 5.0f * cb + b1[n];
    } else if (tid < 33280) {
        int i2 = tid - 16896;
        int j = i2 & 7, lane = (i2 >> 3) & 63, nt = (i2 >> 9) & 7, ks = (i2 >> 12) & 3;
        int k = ks * 32 + (lane >> 4) * 8 + j;
        int n = nt * 16 + (lane & 15);
        wsw2[i2] = f2bf(w2[k*HID + n]);
    }
}

// ===== main =====
__global__ __launch_bounds__(128, 3) void hbond_main(
    const float* __restrict__ x_in,
    const float* __restrict__ c1f, const float* __restrict__ b2,
    const float* __restrict__ g1, const float* __restrict__ be1,
    const float* __restrict__ g2, const float* __restrict__ be2,
    const unsigned short* __restrict__ wswM1, const unsigned short* __restrict__ wsw2,
    float* __restrict__ out, int nItems)
{
    __shared__ __align__(16) unsigned char smem[IPB * SLICE];

    const int l  = threadIdx.x & 63;
    const int wv = threadIdx.x >> 6;
    const int item = blockIdx.x * IPB + wv;
    if (item >= nItems) return;               // wave-uniform; no cross-wave barriers

    unsigned char* slice = smem + wv * SLICE;
    float*          xs   = (float*)(slice);                    // phase A
    unsigned short* adjx = (unsigned short*)(slice + ADJX_OFF);// phase A
    unsigned short* hrm  = (unsigned short*)(slice);           // phase B (aliases A)
    unsigned short* tT   = (unsigned short*)(slice);           // phase C (aliases B)
    unsigned*       resid1 = (unsigned*)(slice + RES1_OFF);    // mt=1 residual

    const int ln15 = l & 15, q = l >> 4;
    const float* xb = x_in + (size_t)item * (N_NODES * IN_DIM);

    // guard for tT col127/q3 overread (bytes 6144..6160)
    if (l == 0) *(u32x4*)(slice + HTSTR * HID * 2) = (u32x4){0,0,0,0};

    // ---- stage x: 180 floats ----
    if (l < 45) ((float4*)xs)[l] = ((const float4*)xb)[l];
    WB();

    // ---- KNN: lane r = row r (r<20); bit-safe d2; tie -> lower index ----
    unsigned nbrp = 0;                        // 5 x 5-bit neighbor indices
    {
        const int rsel = (l < N_NODES) ? l : 0;
        const float px = xs[rsel*IN_DIM+6], py = xs[rsel*IN_DIM+7], pz = xs[rsel*IN_DIM+8];
        float d2[N_NODES];
        #pragma unroll
        for (int j = 0; j < N_NODES; ++j) {
            float dx = __fsub_rn(px, __shfl(px, j));
            float dy = __fsub_rn(py, __shfl(py, j));
            float dz = __fsub_rn(pz, __shfl(pz, j));
            d2[j] = __fadd_rn(__fadd_rn(__fmul_rn(dx,dx), __fmul_rn(dy,dy)), __fmul_rn(dz,dz));
        }
        unsigned used = 0u;
        #pragma unroll
        for (int k = 0; k < K_NBR; ++k) {
            float best = INFINITY; int bi = 0;
            #pragma unroll
            for (int j = 0; j < N_NODES; ++j) {
                bool take = (!((used >> j) & 1u)) && (d2[j] < best);
                best = take ? d2[j] : best;
                bi   = take ? j     : bi;
            }
            used |= (1u << bi);
            nbrp |= (unsigned)bi << (5*k);
        }
    }

    // ---- adjacency bitmask + bf16 A-fragments (k=q*8+j; bits >=20 always 0) ----
    unsigned amask = 0;
    #pragma unroll
    for (int j = 0; j < K_NBR; ++j) amask |= 1u << ((nbrp >> (5*j)) & 31);
    const unsigned am0 = (unsigned)__shfl((int)amask, ln15);
    const unsigned am1 = (unsigned)__shfl((int)amask, ln15 + 16);
    short8 adjf0, adjf1;
    #pragma unroll
    for (int j = 0; j < 8; ++j) {
        adjf0[j] = (short)(((am0 >> (q*8 + j)) & 1u) ? 0x3F80 : 0);
        adjf1[j] = (short)(((am1 >> (q*8 + j)) & 1u) ? 0x3F80 : 0);
    }

    // ---- agg1 on raw x (fp32 exact, packed sums) ----
    if (l < N_NODES) {
        f32x2 s01 = {0,0}, s23 = {0,0}, s45 = {0,0}, s67 = {0,0};
        float s8 = 0.f;
        #pragma unroll
        for (int j = 0; j < K_NBR; ++j) {
            const int b0 = ((nbrp >> (5*j)) & 31) * IN_DIM;
            s01 += (f32x2){xs[b0+0], xs[b0+1]};
            s23 += (f32x2){xs[b0+2], xs[b0+3]};
            s45 += (f32x2){xs[b0+4], xs[b0+5]};
            s67 += (f32x2){xs[b0+6], xs[b0+7]};
            s8  += xs[b0+8];
        }
        u32x4 p0 = { cvtpk(s01.x,s01.y), cvtpk(s23.x,s23.y), cvtpk(s45.x,s45.y), cvtpk(s67.x,s67.y) };
        u32x4 p1 = { cvtpk(s8,0.f), 0, 0, 0 };
        *(u32x4*)&adjx[l*16 + 0] = p0;
        *(u32x4*)&adjx[l*16 + 8] = p1;
    }
    WB();

    f32x4 acc[2][8];
    const int rlo = ln15, rhi = (ln15 + 16 > 19) ? 19 : ln15 + 16;  // clamp garbage rows

    // ---- GEMM1: y1 = adjx @ M1 + c1  (K=32, 16 MFMA; B zero for k>=9) ----
    {
        const short8 a0 = *(const short8*)&adjx[rlo*16 + (q & 1)*8];
        const short8 a1 = *(const short8*)&adjx[rhi*16 + (q & 1)*8];
        #pragma unroll
        for (int nt = 0; nt < 8; ++nt) {
            const float bv = c1f[ln15 + 16*nt];
            f32x4 c0 = (f32x4){bv, bv, bv, bv};
            const short8 bfr = *(const short8*)&wswM1[nt*512 + l*8];
            acc[0][nt] = mfma16(a0, bfr, c0);
            acc[1][nt] = mfma16(a1, bfr, c0);
        }
    }

    // ---- LN1 + GELU (packed f32x2) -> h as packed bf16-pair u32s ----
    unsigned hU01[2][8], hU23[2][8];   // [mt][nt]: rows (reg0,reg1) / (reg2,reg3)
    {
        float gva[8], bva[8];
        #pragma unroll
        for (int nt = 0; nt < 8; ++nt) { gva[nt] = g1[ln15+16*nt]; bva[nt] = be1[ln15+16*nt]; }
        #pragma unroll
        for (int mt = 0; mt < 2; ++mt) {
            f32x2 s01={0,0}, s23={0,0}, t01={0,0}, t23={0,0};
            #pragma unroll
            for (int nt = 0; nt < 8; ++nt) {
                f32x2 v01 = {acc[mt][nt][0], acc[mt][nt][1]};
                f32x2 v23 = {acc[mt][nt][2], acc[mt][nt][3]};
                s01 += v01; s23 += v23;
                t01 += v01*v01; t23 += v23*v23;
            }
            DPP_RED16(s01); DPP_RED16(s23);
            DPP_RED16(t01); DPP_RED16(t23);
            f32x2 mean01 = s01 * (1.f/HID), mean23 = s23 * (1.f/HID);
            f32x2 var01  = t01 * (1.f/HID) - mean01*mean01;
            f32x2 var23  = t23 * (1.f/HID) - mean23*mean23;
            f32x2 rstd01 = { rsqrtf(fmaxf(var01.x,0.f)+EPS), rsqrtf(fmaxf(var01.y,0.f)+EPS) };
            f32x2 rstd23 = { rsqrtf(fmaxf(var23.x,0.f)+EPS), rsqrtf(fmaxf(var23.y,0.f)+EPS) };
            #pragma unroll
            for (int nt = 0; nt < 8; ++nt) {
                f32x2 v01 = {acc[mt][nt][0], acc[mt][nt][1]};
                f32x2 v23 = {acc[mt][nt][2], acc[mt][nt][3]};
                f32x2 h01 = gelu2((v01 - mean01) * rstd01 * gva[nt] + bva[nt]);
                f32x2 h23 = gelu2((v23 - mean23) * rstd23 * gva[nt] + bva[nt]);
                hU01[mt][nt] = cvtpk(h01.x, h01.y);
                hU23[mt][nt] = cvtpk(h23.x, h23.y);
            }
        }
    }
    WB();   // adjx/xs dead; GEMM1 A-reads complete

    // ---- scatter h: hrm row-major (GEMM2' A); mt=0 residual stays in regs,
    //      mt=1 residual (rows 16-19, q==0 lanes) -> resid1 LDS, then regs die ----
    #pragma unroll
    for (int nt = 0; nt < 8; ++nt) {
        const int col = ln15 + 16*nt;
        const unsigned u01 = hU01[0][nt], u23 = hU23[0][nt];
        hrm[(q*4+0)*HRSTR + col] = (unsigned short)u01;
        hrm[(q*4+1)*HRSTR + col] = (unsigned short)(u01 >> 16);
        hrm[(q*4+2)*HRSTR + col] = (unsigned short)u23;
        hrm[(q*4+3)*HRSTR + col] = (unsigned short)(u23 >> 16);
        if (q == 0) {
            const unsigned v01 = hU01[1][nt], v23 = hU23[1][nt];
            hrm[16*HRSTR + col] = (unsigned short)v01;
            hrm[17*HRSTR + col] = (unsigned short)(v01 >> 16);
            hrm[18*HRSTR + col] = (unsigned short)v23;
            hrm[19*HRSTR + col] = (unsigned short)(v23 >> 16);
            *(u32x2*)&resid1[(nt*16 + ln15)*2] = (u32x2){v01, v23};
        }
    }
    WB();

    // ---- GEMM2': t = h @ W2  (K=128, 64 MFMA; garbage rows clamped) ----
    #pragma unroll
    for (int nt = 0; nt < 8; ++nt) { acc[0][nt] = (f32x4){0,0,0,0}; acc[1][nt] = acc[0][nt]; }
    #pragma unroll
    for (int ks = 0; ks < 4; ++ks) {
        const short8 a0 = *(const short8*)&hrm[rlo*HRSTR + ks*32 + q*8];
        const short8 a1 = *(const short8*)&hrm[rhi*HRSTR + ks*32 + q*8];
        #pragma unroll
        for (int nt = 0; nt < 8; ++nt) {
            const short8 bfr = *(const short8*)&wsw2[(ks*8 + nt)*512 + l*8];
            acc[0][nt] = mfma16(a0, bfr, acc[0][nt]);
            acc[1][nt] = mfma16(a1, bfr, acc[1][nt]);
        }
    }
    WB();   // all hrm reads complete; tT may overwrite

    // ---- store t transposed: tT[col][row] ----
    #pragma unroll
    for (int nt = 0; nt < 8; ++nt) {
        const int col = ln15 + 16*nt;
        u32x2 w0 = { cvtpk(acc[0][nt][0], acc[0][nt][1]), cvtpk(acc[0][nt][2], acc[0][nt][3]) };
        *(u32x2*)&tT[col*HTSTR + q*4] = w0;
        if (q == 0) {
            u32x2 w1v = { cvtpk(acc[1][nt][0], acc[1][nt][1]), cvtpk(acc[1][nt][2], acc[1][nt][3]) };
            *(u32x2*)&tT[col*HTSTR + 16] = w1v;
        }
    }
    // zero row-slots 20..23 (stale bytes can encode Inf/NaN; 0*Inf = NaN in MFMA)
    *(u32x2*)&tT[l*HTSTR + 20]        = (u32x2){0,0};
    *(u32x2*)&tT[(l + 64)*HTSTR + 20] = (u32x2){0,0};
    WB();

    // ---- y2 = adj @ t + b2  (16 MFMA; reuse acc) ----
    #pragma unroll
    for (int nt = 0; nt < 8; ++nt) {
        const float bv = b2[ln15 + 16*nt];
        f32x4 c0 = (f32x4){bv, bv, bv, bv};
        const short8 bfr = *(const short8*)&tT[(ln15 + 16*nt)*HTSTR + q*8];
        acc[0][nt] = mfma16(adjf0, bfr, c0);
        acc[1][nt] = mfma16(adjf1, bfr, c0);
    }

    // ---- LN2 stats (packed, DPP reduce) ----
    f32x2 mean01[2], mean23[2], rstd01[2], rstd23[2];
    #pragma unroll
    for (int mt = 0; mt < 2; ++mt) {
        f32x2 s01={0,0}, s23={0,0}, t01={0,0}, t23={0,0};
        #pragma unroll
        for (int nt = 0; nt < 8; ++nt) {
            f32x2 v01 = {acc[mt][nt][0], acc[mt][nt][1]};
            f32x2 v23 = {acc[mt][nt][2], acc[mt][nt][3]};
            s01 += v01; s23 += v23;
            t01 += v01*v01; t23 += v23*v23;
        }
        DPP_RED16(s01); DPP_RED16(s23);
        DPP_RED16(t01); DPP_RED16(t23);
        mean01[mt] = s01 * (1.f/HID); mean23[mt] = s23 * (1.f/HID);
        f32x2 v01 = t01 * (1.f/HID) - mean01[mt]*mean01[mt];
        f32x2 v23 = t23 * (1.f/HID) - mean23[mt]*mean23[mt];
        rstd01[mt] = (f32x2){ rsqrtf(fmaxf(v01.x,0.f)+EPS), rsqrtf(fmaxf(v01.y,0.f)+EPS) };
        rstd23[mt] = (f32x2){ rsqrtf(fmaxf(v23.x,0.f)+EPS), rsqrtf(fmaxf(v23.y,0.f)+EPS) };
    }

    // ---- fused LN2-apply + residual + minmax + gelu + store ----
    // gelu unimodal: max over rows = max(gelu(rmin), gelu(rmax))
    #pragma unroll
    for (int nt = 0; nt < 8; ++nt) {
        const int col = ln15 + 16*nt;
        const float gv = g2[col], bv = be2[col];
        f32x2 y01 = ((f32x2){acc[0][nt][0], acc[0][nt][1]} - mean01[0]) * rstd01[0] * gv + bv;
        f32x2 y23 = ((f32x2){acc[0][nt][2], acc[0][nt][3]} - mean23[0]) * rstd23[0] * gv + bv;
        f32x2 r01 = y01 + unpk(hU01[0][nt]);
        f32x2 r23 = y23 + unpk(hU23[0][nt]);
        float rmax = fmaxf(fmaxf(r01.x, r01.y), fmaxf(r23.x, r23.y));
        float rmin = fminf(fminf(r01.x, r01.y), fminf(r23.x, r23.y));
        if (q == 0) {
            f32x2 z01 = ((f32x2){acc[1][nt][0], acc[1][nt][1]} - mean01[1]) * rstd01[1] * gv + bv;
            f32x2 z23 = ((f32x2){acc[1][nt][2], acc[1][nt][3]} - mean23[1]) * rstd23[1] * gv + bv;
            const u32x2 hx = *(const u32x2*)&resid1[(nt*16 + ln15)*2];
            f32x2 w01 = z01 + unpk(hx.x);
            f32x2 w23 = z23 + unpk(hx.y);
            rmax = fmaxf(rmax, fmaxf(fmaxf(w01.x, w01.y), fmaxf(w23.x, w23.y)));
            rmin = fminf(rmin, fminf(fminf(w01.x, w01.y), fminf(w23.x, w23.y)));
        }
        rmax = fmaxf(rmax, __shfl_xor(rmax, 16)); rmin = fminf(rmin, __shfl_xor(rmin, 16));
        rmax = fmaxf(rmax, __shfl_xor(rmax, 32)); rmin = fminf(rmin, __shfl_xor(rmin, 32));
        const float m0 = fmaxf(gelu_fast(rmax), gelu_fast(rmin));
        if (l < 16) out[(size_t)item*HID + 16*nt + l] = m0;
    }
}

extern "C" void kernel_launch(void* const* d_in, const int* in_sizes, int n_in,
                              void* d_out, int out_size, void* d_ws, size_t ws_size,
                              hipStream_t stream) {
    (void)n_in; (void)out_size; (void)ws_size;
    const float* x       = (const float*)d_in[0];
    const float* w_embed = (const float*)d_in[1];
    const float* b_embed = (const float*)d_in[2];
    const float* w1      = (const float*)d_in[3];
    const float* b1      = (const float*)d_in[4];
    const float* w2      = (const float*)d_in[5];
    const float* b2      = (const float*)d_in[6];
    const float* g1      = (const float*)d_in[7];
    const float* be1     = (const float*)d_in[8];
    const float* g2      = (const float*)d_in[9];
    const float* be2     = (const float*)d_in[10];
    float* out = (float*)d_out;

    // ws layout: [c1f 512B][wswM1 8192B][wsw2 32768B]
    unsigned char* ws = (unsigned char*)d_ws;
    float* c1f            = (float*)(ws + 0);
    unsigned short* wswM1 = (unsigned short*)(ws + 512);
    unsigned short* wsw2  = (unsigned short*)(ws + 512 + 8192);

    const int nItems  = in_sizes[0] / (N_NODES * IN_DIM);
    const int nBlocks = (nItems + IPB - 1) / IPB;

    prep_all<<<dim3(130), dim3(256), 0, stream>>>(w_embed, b_embed, w1, b1, w2,
                                                  wswM1, wsw2, c1f);
    hbond_main<<<dim3(nBlocks), dim3(128), 0, stream>>>(
        x, c1f, b2, g1, be1, g2, be2, wswM1, wsw2, out, nItems);
}

// Round 6
// 272.733 us; speedup vs baseline: 1.4141x; 1.0583x over previous
//
#include <hip/hip_runtime.h>
#include <math.h>

#define N_NODES 20
#define IN_DIM  9
#define HID     128
#define K_NBR   5
#define EPS     1e-5f
#define IPB     2          // items (waves) per 128-thread block

// ---- per-item LDS slice (bytes), regions with disjoint lifetimes alias at 0 ----
// phase A: xs (180 f32 = 720B @0) + adjx (20x16 bf16 = 640B @736)
// phase B: hrm (20 rows x 136 bf16 = 5440B @0)   h row-major, A-operand for t=h@W2
// phase C: tT  (128 cols x 24 bf16 = 6144B @0)   t transposed, B-operand for adj@t
// guard  : 16B zeros @6144 (col127/q3 B-frag overread target; never clobbered)
// resid1 : mt=1 residual rows 16-19, [nt][ln15] u32x2 = 1024B @6160 (scatter->final)
//          (aliased during phase A by pos4: 20 x float4 KNN position table)
// mt=0 residual stays in REGISTERS (hU01/hU23). 64-AGPR dual-mt accumulator kept:
// natural unified usage ~148 regs -> 3 waves/SIMD is the ceiling (bound-4 spills,
// measured rounds 2 & 4). Round 6: 2-way cooperative KNN + exp2-folded gelu.
#define ADJX_OFF  736
#define RES1_OFF  6160
#define SLICE     7184
#define HTSTR     24       // tT row-slots per col (multiple of 8 -> b128-aligned reads)
#define HRSTR     136      // hrm row stride (272B: 16B-mult, 4 mod 32 banks -> 2-way free)

typedef __attribute__((ext_vector_type(8))) short short8;   // 8 bf16 (4 VGPRs)
typedef __attribute__((ext_vector_type(4))) float f32x4;    // MFMA C/D frag
typedef __attribute__((ext_vector_type(2))) float f32x2;    // v_pk_*_f32 carrier
typedef __attribute__((ext_vector_type(2))) unsigned int u32x2;
typedef __attribute__((ext_vector_type(4))) unsigned int u32x4;

#define WB() __builtin_amdgcn_wave_barrier()

__device__ __forceinline__ unsigned short f2bf(float f) {
    unsigned u = __builtin_bit_cast(unsigned, f);
    u += 0x7fffu + ((u >> 16) & 1u);          // RNE
    return (unsigned short)(u >> 16);
}
#if __has_builtin(__builtin_amdgcn_cvt_pk_bf16_f32)
typedef __attribute__((ext_vector_type(2))) __bf16 bf16x2;
__device__ __forceinline__ unsigned cvtpk(float a, float b) {   // low=bf16(a), hi=bf16(b)
    bf16x2 r = __builtin_amdgcn_cvt_pk_bf16_f32(a, b);
    return __builtin_bit_cast(unsigned, r);
}
#else
__device__ __forceinline__ unsigned cvtpk(float a, float b) {
    return (unsigned)f2bf(a) | ((unsigned)f2bf(b) << 16);
}
#endif
// unpack a bf16 pair (one u32) to two floats: lo = bits<<16, hi = bits&0xffff0000
__device__ __forceinline__ f32x2 unpk(unsigned u) {
    return (f32x2){ __builtin_bit_cast(float, u << 16),
                    __builtin_bit_cast(float, u & 0xffff0000u) };
}
// exp2 direct (v_exp_f32 computes 2^x); fallback keeps old __expf path
#if __has_builtin(__builtin_amdgcn_exp2f)
#define EXP2F(x) __builtin_amdgcn_exp2f(x)
#else
#define EXP2F(x) __expf((x) * 0.6931471806f)
#endif
// tanh-form GELU (|err| <~1e-3): x*u/(u+1), u=2^{log2e*2*0.79788456*(x+0.044715x^3)}
// constants pre-scaled by log2(e): 0.07135806592*1.44269504 = 0.10294793,
//                                  1.59576912  *1.44269504 = 2.30220802
__device__ __forceinline__ float gelu_fast(float x) {
    float x2 = x * x;
    float y  = x * fmaf(x2, 0.10294793f, 2.30220802f);
    float u  = EXP2F(fminf(y, 87.0f));
    return x * u * __builtin_amdgcn_rcpf(u + 1.0f);
}
// packed 2-element gelu: polynomial in v_pk_*, exp/rcp scalar (no pk transcendentals)
__device__ __forceinline__ f32x2 gelu2(f32x2 x) {
    f32x2 x2 = x * x;
    f32x2 y  = x * (x2 * 0.10294793f + 2.30220802f);
    f32x2 u  = { EXP2F(fminf(y.x, 87.0f)), EXP2F(fminf(y.y, 87.0f)) };
    f32x2 n  = x * u;
    f32x2 d  = u + 1.0f;
    return (f32x2){ n.x * __builtin_amdgcn_rcpf(d.x), n.y * __builtin_amdgcn_rcpf(d.y) };
}
__device__ __forceinline__ f32x2 shfl2(f32x2 v, int m) {
    return (f32x2){ __shfl_xor(v.x, m), __shfl_xor(v.y, m) };
}

// ---- DPP cross-lane (pure VALU, no DS pipe / lgkmcnt) ----
// 16-lane all-reduce via xor-levels {1,2,7,8}: a GF(2) basis of [0,16)
// (7 = 1^2^4 so 4 is in the span). All four exist as DPP ctrls:
//   xor1 = quad_perm[1,0,3,2] (0xB1), xor2 = quad_perm[2,3,0,1] (0x4E),
//   xor7 = row_half_mirror (0x141),   xor8 = row_ror:8 (0x128).
template<int CTRL>
__device__ __forceinline__ float dppf(float v) {
    int i = __builtin_bit_cast(int, v);
    return __builtin_bit_cast(float,
        __builtin_amdgcn_update_dpp(i, i, CTRL, 0xF, 0xF, false));
}
template<int CTRL>
__device__ __forceinline__ f32x2 dpp2(f32x2 v) {
    return (f32x2){ dppf<CTRL>(v.x), dppf<CTRL>(v.y) };
}
#define DPP_RED16(V) { V += dpp2<0xB1>(V); V += dpp2<0x4E>(V); \
                       V += dpp2<0x141>(V); V += dpp2<0x128>(V); }

__device__ __forceinline__ f32x4 mfma16(short8 a, short8 b, f32x4 c) {
    return __builtin_amdgcn_mfma_f32_16x16x32_bf16(a, b, c, 0, 0, 0);
}

// ===== single prep kernel, fully parallel =====
__global__ void prep_all(const float* __restrict__ w_embed, const float* __restrict__ b_embed,
                         const float* __restrict__ w1, const float* __restrict__ b1,
                         const float* __restrict__ w2,
                         unsigned short* __restrict__ wswM1, unsigned short* __restrict__ wsw2,
                         float* __restrict__ c1f) {
    int tid = blockIdx.x * 256 + threadIdx.x;          // 33280 total -> 130 blocks
    if (tid < 16384) {
        int oid = tid >> 2, sub = tid & 3;
        int j = oid & 7, lane = (oid >> 3) & 63, nt = (oid >> 9) & 7;
        int k = (lane >> 4) * 8 + j;
        int n = nt * 16 + (lane & 15);
        float acc = 0.f;
        if (k < IN_DIM) {
            #pragma unroll 8
            for (int c = sub * 32; c < sub * 32 + 32; ++c)
                acc = fmaf(w_embed[k*HID + c], w1[c*HID + n], acc);
        }
        acc += __shfl_xor(acc, 1);
        acc += __shfl_xor(acc, 2);
        if (sub == 0) wswM1[oid] = (k < IN_DIM) ? f2bf(acc) : (unsigned short)0;
    } else if (tid < 16896) {
        int t2 = tid - 16384;
        int n = t2 >> 2, sub = t2 & 3;
        float cb = 0.f;
        #pragma unroll 8
        for (int c = sub * 32; c < sub * 32 + 32; ++c)
            cb = fmaf(b_embed[c], w1[c*HID + n], cb);
        cb += __shfl_xor(cb, 1);
        cb += __shfl_xor(cb, 2);
        if (sub == 0) c1f[n] = 5.0f * cb + b1[n];
    } else if (tid < 33280) {
        int i2 = tid - 16896;
        int j = i2 & 7, lane = (i2 >> 3) & 63, nt = (i2 >> 9) & 7, ks = (i2 >> 12) & 3;
        int k = ks * 32 + (lane >> 4) * 8 + j;
        int n = nt * 16 + (lane & 15);
        wsw2[i2] = f2bf(w2[k*HID + n]);
    }
}

// ===== main =====
__global__ __launch_bounds__(128, 3) void hbond_main(
    const float* __restrict__ x_in,
    const float* __restrict__ c1f, const float* __restrict__ b2,
    const float* __restrict__ g1, const float* __restrict__ be1,
    const float* __restrict__ g2, const float* __restrict__ be2,
    const unsigned short* __restrict__ wswM1, const unsigned short* __restrict__ wsw2,
    float* __restrict__ out, int nItems)
{
    __shared__ __align__(16) unsigned char smem[IPB * SLICE];

    const int l  = threadIdx.x & 63;
    const int wv = threadIdx.x >> 6;
    const int item = blockIdx.x * IPB + wv;
    if (item >= nItems) return;               // wave-uniform; no cross-wave barriers

    unsigned char* slice = smem + wv * SLICE;
    float*          xs   = (float*)(slice);                    // phase A
    unsigned short* adjx = (unsigned short*)(slice + ADJX_OFF);// phase A
    unsigned short* hrm  = (unsigned short*)(slice);           // phase B (aliases A)
    unsigned short* tT   = (unsigned short*)(slice);           // phase C (aliases B)
    unsigned*       resid1 = (unsigned*)(slice + RES1_OFF);    // mt=1 residual
    float4*         pos4 = (float4*)(slice + RES1_OFF);        // KNN pos table (phase A)

    const int ln15 = l & 15, q = l >> 4;
    const float* xb = x_in + (size_t)item * (N_NODES * IN_DIM);

    // guard for tT col127/q3 overread (bytes 6144..6160)
    if (l == 0) *(u32x4*)(slice + HTSTR * HID * 2) = (u32x4){0,0,0,0};

    // ---- stage x: 180 floats ----
    if (l < 45) ((float4*)xs)[l] = ((const float4*)xb)[l];
    WB();

    // ---- KNN, 2-way cooperative: rows in lanes l&31 (dup in 32-51); each
    //      partner pair splits the 20 candidates 10/10. d2 bit-exact; local
    //      argmin strict-< (tie->lowest local j), cross-merge tie->group 0
    //      (lower indices) => identical result to global scan. ----
    const int r = l & 31;
    const int rsel = (r < N_NODES) ? r : 0;
    const float px = xs[rsel*IN_DIM+6], py = xs[rsel*IN_DIM+7], pz = xs[rsel*IN_DIM+8];
    if (l < N_NODES) pos4[l] = (float4){px, py, pz, 0.f};
    WB();

    unsigned nbrp = 0;                        // 5 x 5-bit neighbor indices
    {
        const int jbase = (l >> 5) * 10;      // my candidate window [jbase, jbase+10)
        float d2[10];
        #pragma unroll
        for (int jj = 0; jj < 10; ++jj) {
            const float4 p = pos4[jbase + jj];
            float dx = __fsub_rn(px, p.x);
            float dy = __fsub_rn(py, p.y);
            float dz = __fsub_rn(pz, p.z);
            d2[jj] = __fadd_rn(__fadd_rn(__fmul_rn(dx,dx), __fmul_rn(dy,dy)), __fmul_rn(dz,dz));
        }
        unsigned used = 0u;
        #pragma unroll
        for (int k = 0; k < K_NBR; ++k) {
            float mb = INFINITY; int mj = jbase;
            #pragma unroll
            for (int jj = 0; jj < 10; ++jj) {
                bool take = (!((used >> jj) & 1u)) && (d2[jj] < mb);
                mb = take ? d2[jj] : mb;
                mj = take ? jbase + jj : mj;
            }
            const float pb = __shfl_xor(mb, 32);
            const int   pj = __shfl_xor(mj, 32);
            const bool pwin = (pb < mb) || ((pb == mb) && (pj < mj));
            const int wj = pwin ? pj : mj;
            if (!pwin) used |= 1u << (mj - jbase);
            nbrp |= (unsigned)wj << (5*k);
        }
    }

    // ---- adjacency bitmask + bf16 A-fragments (k=q*8+j; bits >=20 always 0) ----
    unsigned amask = 0;
    #pragma unroll
    for (int j = 0; j < K_NBR; ++j) amask |= 1u << ((nbrp >> (5*j)) & 31);
    const unsigned am0 = (unsigned)__shfl((int)amask, ln15);
    const unsigned am1 = (unsigned)__shfl((int)amask, ln15 + 16);
    short8 adjf0, adjf1;
    #pragma unroll
    for (int j = 0; j < 8; ++j) {
        adjf0[j] = (short)(((am0 >> (q*8 + j)) & 1u) ? 0x3F80 : 0);
        adjf1[j] = (short)(((am1 >> (q*8 + j)) & 1u) ? 0x3F80 : 0);
    }

    // ---- agg1 on raw x (fp32 exact, packed sums) ----
    if (l < N_NODES) {
        f32x2 s01 = {0,0}, s23 = {0,0}, s45 = {0,0}, s67 = {0,0};
        float s8 = 0.f;
        #pragma unroll
        for (int j = 0; j < K_NBR; ++j) {
            const int b0 = ((nbrp >> (5*j)) & 31) * IN_DIM;
            s01 += (f32x2){xs[b0+0], xs[b0+1]};
            s23 += (f32x2){xs[b0+2], xs[b0+3]};
            s45 += (f32x2){xs[b0+4], xs[b0+5]};
            s67 += (f32x2){xs[b0+6], xs[b0+7]};
            s8  += xs[b0+8];
        }
        u32x4 p0 = { cvtpk(s01.x,s01.y), cvtpk(s23.x,s23.y), cvtpk(s45.x,s45.y), cvtpk(s67.x,s67.y) };
        u32x4 p1 = { cvtpk(s8,0.f), 0, 0, 0 };
        *(u32x4*)&adjx[l*16 + 0] = p0;
        *(u32x4*)&adjx[l*16 + 8] = p1;
    }
    WB();

    f32x4 acc[2][8];
    const int rlo = ln15, rhi = (ln15 + 16 > 19) ? 19 : ln15 + 16;  // clamp garbage rows

    // ---- GEMM1: y1 = adjx @ M1 + c1  (K=32, 16 MFMA; B zero for k>=9) ----
    {
        const short8 a0 = *(const short8*)&adjx[rlo*16 + (q & 1)*8];
        const short8 a1 = *(const short8*)&adjx[rhi*16 + (q & 1)*8];
        #pragma unroll
        for (int nt = 0; nt < 8; ++nt) {
            const float bv = c1f[ln15 + 16*nt];
            f32x4 c0 = (f32x4){bv, bv, bv, bv};
            const short8 bfr = *(const short8*)&wswM1[nt*512 + l*8];
            acc[0][nt] = mfma16(a0, bfr, c0);
            acc[1][nt] = mfma16(a1, bfr, c0);
        }
    }

    // ---- LN1 + GELU (packed f32x2) -> h as packed bf16-pair u32s ----
    unsigned hU01[2][8], hU23[2][8];   // [mt][nt]: rows (reg0,reg1) / (reg2,reg3)
    {
        float gva[8], bva[8];
        #pragma unroll
        for (int nt = 0; nt < 8; ++nt) { gva[nt] = g1[ln15+16*nt]; bva[nt] = be1[ln15+16*nt]; }
        #pragma unroll
        for (int mt = 0; mt < 2; ++mt) {
            f32x2 s01={0,0}, s23={0,0}, t01={0,0}, t23={0,0};
            #pragma unroll
            for (int nt = 0; nt < 8; ++nt) {
                f32x2 v01 = {acc[mt][nt][0], acc[mt][nt][1]};
                f32x2 v23 = {acc[mt][nt][2], acc[mt][nt][3]};
                s01 += v01; s23 += v23;
                t01 += v01*v01; t23 += v23*v23;
            }
            DPP_RED16(s01); DPP_RED16(s23);
            DPP_RED16(t01); DPP_RED16(t23);
            f32x2 mean01 = s01 * (1.f/HID), mean23 = s23 * (1.f/HID);
            f32x2 var01  = t01 * (1.f/HID) - mean01*mean01;
            f32x2 var23  = t23 * (1.f/HID) - mean23*mean23;
            f32x2 rstd01 = { rsqrtf(fmaxf(var01.x,0.f)+EPS), rsqrtf(fmaxf(var01.y,0.f)+EPS) };
            f32x2 rstd23 = { rsqrtf(fmaxf(var23.x,0.f)+EPS), rsqrtf(fmaxf(var23.y,0.f)+EPS) };
            #pragma unroll
            for (int nt = 0; nt < 8; ++nt) {
                f32x2 v01 = {acc[mt][nt][0], acc[mt][nt][1]};
                f32x2 v23 = {acc[mt][nt][2], acc[mt][nt][3]};
                f32x2 h01 = gelu2((v01 - mean01) * rstd01 * gva[nt] + bva[nt]);
                f32x2 h23 = gelu2((v23 - mean23) * rstd23 * gva[nt] + bva[nt]);
                hU01[mt][nt] = cvtpk(h01.x, h01.y);
                hU23[mt][nt] = cvtpk(h23.x, h23.y);
            }
        }
    }
    WB();   // adjx/xs dead; GEMM1 A-reads complete

    // ---- scatter h: hrm row-major (GEMM2' A); mt=0 residual stays in regs,
    //      mt=1 residual (rows 16-19, q==0 lanes) -> resid1 LDS, then regs die ----
    #pragma unroll
    for (int nt = 0; nt < 8; ++nt) {
        const int col = ln15 + 16*nt;
        const unsigned u01 = hU01[0][nt], u23 = hU23[0][nt];
        hrm[(q*4+0)*HRSTR + col] = (unsigned short)u01;
        hrm[(q*4+1)*HRSTR + col] = (unsigned short)(u01 >> 16);
        hrm[(q*4+2)*HRSTR + col] = (unsigned short)u23;
        hrm[(q*4+3)*HRSTR + col] = (unsigned short)(u23 >> 16);
        if (q == 0) {
            const unsigned v01 = hU01[1][nt], v23 = hU23[1][nt];
            hrm[16*HRSTR + col] = (unsigned short)v01;
            hrm[17*HRSTR + col] = (unsigned short)(v01 >> 16);
            hrm[18*HRSTR + col] = (unsigned short)v23;
            hrm[19*HRSTR + col] = (unsigned short)(v23 >> 16);
            *(u32x2*)&resid1[(nt*16 + ln15)*2] = (u32x2){v01, v23};
        }
    }
    WB();

    // ---- GEMM2': t = h @ W2  (K=128, 64 MFMA; garbage rows clamped) ----
    #pragma unroll
    for (int nt = 0; nt < 8; ++nt) { acc[0][nt] = (f32x4){0,0,0,0}; acc[1][nt] = acc[0][nt]; }
    #pragma unroll
    for (int ks = 0; ks < 4; ++ks) {
        const short8 a0 = *(const short8*)&hrm[rlo*HRSTR + ks*32 + q*8];
        const short8 a1 = *(const short8*)&hrm[rhi*HRSTR + ks*32 + q*8];
        #pragma unroll
        for (int nt = 0; nt < 8; ++nt) {
            const short8 bfr = *(const short8*)&wsw2[(ks*8 + nt)*512 + l*8];
            acc[0][nt] = mfma16(a0, bfr, acc[0][nt]);
            acc[1][nt] = mfma16(a1, bfr, acc[1][nt]);
        }
    }
    WB();   // all hrm reads complete; tT may overwrite

    // ---- store t transposed: tT[col][row] ----
    #pragma unroll
    for (int nt = 0; nt < 8; ++nt) {
        const int col = ln15 + 16*nt;
        u32x2 w0 = { cvtpk(acc[0][nt][0], acc[0][nt][1]), cvtpk(acc[0][nt][2], acc[0][nt][3]) };
        *(u32x2*)&tT[col*HTSTR + q*4] = w0;
        if (q == 0) {
            u32x2 w1v = { cvtpk(acc[1][nt][0], acc[1][nt][1]), cvtpk(acc[1][nt][2], acc[1][nt][3]) };
            *(u32x2*)&tT[col*HTSTR + 16] = w1v;
        }
    }
    // zero row-slots 20..23 (stale bytes can encode Inf/NaN; 0*Inf = NaN in MFMA)
    *(u32x2*)&tT[l*HTSTR + 20]        = (u32x2){0,0};
    *(u32x2*)&tT[(l + 64)*HTSTR + 20] = (u32x2){0,0};
    WB();

    // ---- y2 = adj @ t + b2  (16 MFMA; reuse acc) ----
    #pragma unroll
    for (int nt = 0; nt < 8; ++nt) {
        const float bv = b2[ln15 + 16*nt];
        f32x4 c0 = (f32x4){bv, bv, bv, bv};
        const short8 bfr = *(const short8*)&tT[(ln15 + 16*nt)*HTSTR + q*8];
        acc[0][nt] = mfma16(adjf0, bfr, c0);
        acc[1][nt] = mfma16(adjf1, bfr, c0);
    }

    // ---- LN2 stats (packed, DPP reduce) ----
    f32x2 mean01[2], mean23[2], rstd01[2], rstd23[2];
    #pragma unroll
    for (int mt = 0; mt < 2; ++mt) {
        f32x2 s01={0,0}, s23={0,0}, t01={0,0}, t23={0,0};
        #pragma unroll
        for (int nt = 0; nt < 8; ++nt) {
            f32x2 v01 = {acc[mt][nt][0], acc[mt][nt][1]};
            f32x2 v23 = {acc[mt][nt][2], acc[mt][nt][3]};
            s01 += v01; s23 += v23;
            t01 += v01*v01; t23 += v23*v23;
        }
        DPP_RED16(s01); DPP_RED16(s23);
        DPP_RED16(t01); DPP_RED16(t23);
        mean01[mt] = s01 * (1.f/HID); mean23[mt] = s23 * (1.f/HID);
        f32x2 v01 = t01 * (1.f/HID) - mean01[mt]*mean01[mt];
        f32x2 v23 = t23 * (1.f/HID) - mean23[mt]*mean23[mt];
        rstd01[mt] = (f32x2){ rsqrtf(fmaxf(v01.x,0.f)+EPS), rsqrtf(fmaxf(v01.y,0.f)+EPS) };
        rstd23[mt] = (f32x2){ rsqrtf(fmaxf(v23.x,0.f)+EPS), rsqrtf(fmaxf(v23.y,0.f)+EPS) };
    }

    // ---- fused LN2-apply + residual + minmax + gelu + store ----
    // gelu unimodal: max over rows = max(gelu(rmin), gelu(rmax))
    #pragma unroll
    for (int nt = 0; nt < 8; ++nt) {
        const int col = ln15 + 16*nt;
        const float gv = g2[col], bv = be2[col];
        f32x2 y01 = ((f32x2){acc[0][nt][0], acc[0][nt][1]} - mean01[0]) * rstd01[0] * gv + bv;
        f32x2 y23 = ((f32x2){acc[0][nt][2], acc[0][nt][3]} - mean23[0]) * rstd23[0] * gv + bv;
        f32x2 r01 = y01 + unpk(hU01[0][nt]);
        f32x2 r23 = y23 + unpk(hU23[0][nt]);
        float rmax = fmaxf(fmaxf(r01.x, r01.y), fmaxf(r23.x, r23.y));
        float rmin = fminf(fminf(r01.x, r01.y), fminf(r23.x, r23.y));
        if (q == 0) {
            f32x2 z01 = ((f32x2){acc[1][nt][0], acc[1][nt][1]} - mean01[1]) * rstd01[1] * gv + bv;
            f32x2 z23 = ((f32x2){acc[1][nt][2], acc[1][nt][3]} - mean23[1]) * rstd23[1] * gv + bv;
            const u32x2 hx = *(const u32x2*)&resid1[(nt*16 + ln15)*2];
            f32x2 w01 = z01 + unpk(hx.x);
            f32x2 w23 = z23 + unpk(hx.y);
            rmax = fmaxf(rmax, fmaxf(fmaxf(w01.x, w01.y), fmaxf(w23.x, w23.y)));
            rmin = fminf(rmin, fminf(fminf(w01.x, w01.y), fminf(w23.x, w23.y)));
        }
        rmax = fmaxf(rmax, __shfl_xor(rmax, 16)); rmin = fminf(rmin, __shfl_xor(rmin, 16));
        rmax = fmaxf(rmax, __shfl_xor(rmax, 32)); rmin = fminf(rmin, __shfl_xor(rmin, 32));
        const f32x2 gmm = gelu2((f32x2){rmin, rmax});
        const float m0 = fmaxf(gmm.x, gmm.y);
        if (l < 16) out[(size_t)item*HID + 16*nt + l] = m0;
    }
}

extern "C" void kernel_launch(void* const* d_in, const int* in_sizes, int n_in,
                              void* d_out, int out_size, void* d_ws, size_t ws_size,
                              hipStream_t stream) {
    (void)n_in; (void)out_size; (void)ws_size;
    const float* x       = (const float*)d_in[0];
    const float* w_embed = (const float*)d_in[1];
    const float* b_embed = (const float*)d_in[2];
    const float* w1      = (const float*)d_in[3];
    const float* b1      = (const float*)d_in[4];
    const float* w2      = (const float*)d_in[5];
    const float* b2      = (const float*)d_in[6];
    const float* g1      = (const float*)d_in[7];
    const float* be1     = (const float*)d_in[8];
    const float* g2      = (const float*)d_in[9];
    const float* be2     = (const float*)d_in[10];
    float* out = (float*)d_out;

    // ws layout: [c1f 512B][wswM1 8192B][wsw2 32768B]
    unsigned char* ws = (unsigned char*)d_ws;
    float* c1f            = (float*)(ws + 0);
    unsigned short* wswM1 = (unsigned short*)(ws + 512);
    unsigned short* wsw2  = (unsigned short*)(ws + 512 + 8192);

    const int nItems  = in_sizes[0] / (N_NODES * IN_DIM);
    const int nBlocks = (nItems + IPB - 1) / IPB;

    prep_all<<<dim3(130), dim3(256), 0, stream>>>(w_embed, b_embed, w1, b1, w2,
                                                  wswM1, wsw2, c1f);
    hbond_main<<<dim3(nBlocks), dim3(128), 0, stream>>>(
        x, c1f, b2, g1, be1, g2, be2, wswM1, wsw2, out, nItems);
}

// Round 9
// 270.067 us; speedup vs baseline: 1.4280x; 1.0099x over previous
//
#include <hip/hip_runtime.h>
#include <math.h>

#define N_NODES 20
#define IN_DIM  9
#define HID     128
#define K_NBR   5
#define EPS     1e-5f
#define IPB     2          // items (waves) per 128-thread block

// ---- per-item LDS slice (bytes), regions with disjoint lifetimes alias at 0 ----
// phase A: xs (180 f32 = 720B @0) + adjx (20x16 bf16 = 640B @736)
// phase B: hrm (20 rows x 136 bf16 = 5440B @0)   h row-major, A-operand for t=h@W2
// phase C: tT  (128 cols x 24 bf16 = 6144B @0)   t transposed, B-operand for adj@t
// guard  : 16B zeros @6144 (col127/q3 B-frag overread target; never clobbered)
// resid1 : mt=1 residual rows 16-19, [nt][ln15] u32x2 = 1024B @6160 (scatter->final)
//          (aliased during phase A by pos4: 20 x float4 KNN position table)
// mt=0 residual stays in REGISTERS (hU01/hU23). 64-AGPR dual-mt accumulator kept:
// natural unified usage ~148 regs -> 3 waves/SIMD ceiling (bound-4 spills, r2/r4).
// LESSONS: (r7) no hand-written v_mfma asm — hazard recognizer can't see it.
//          (r8) permlane16/32_swap builtins gave wrong-partner merges — only
//          shfl_xor / verified DPP idioms are trusted for cross-lane.
// Round 9: round-6 base + clamp-free reciprocal GELU: x*rcp(1+2^-y) — same math,
// no fminf clamps, no x*u multiply (saves ~3 inst x 80 gelu2/item).
#define ADJX_OFF  736
#define RES1_OFF  6160
#define SLICE     7184
#define HTSTR     24       // tT row-slots per col (multiple of 8 -> b128-aligned reads)
#define HRSTR     136      // hrm row stride (272B: 16B-mult, 4 mod 32 banks -> 2-way free)

typedef __attribute__((ext_vector_type(8))) short short8;   // 8 bf16 (4 VGPRs)
typedef __attribute__((ext_vector_type(4))) float f32x4;    // MFMA C/D frag
typedef __attribute__((ext_vector_type(2))) float f32x2;    // v_pk_*_f32 carrier
typedef __attribute__((ext_vector_type(2))) unsigned int u32x2;
typedef __attribute__((ext_vector_type(4))) unsigned int u32x4;

#define WB() __builtin_amdgcn_wave_barrier()

__device__ __forceinline__ unsigned short f2bf(float f) {
    unsigned u = __builtin_bit_cast(unsigned, f);
    u += 0x7fffu + ((u >> 16) & 1u);          // RNE
    return (unsigned short)(u >> 16);
}
#if __has_builtin(__builtin_amdgcn_cvt_pk_bf16_f32)
typedef __attribute__((ext_vector_type(2))) __bf16 bf16x2;
__device__ __forceinline__ unsigned cvtpk(float a, float b) {   // low=bf16(a), hi=bf16(b)
    bf16x2 r = __builtin_amdgcn_cvt_pk_bf16_f32(a, b);
    return __builtin_bit_cast(unsigned, r);
}
#else
__device__ __forceinline__ unsigned cvtpk(float a, float b) {
    return (unsigned)f2bf(a) | ((unsigned)f2bf(b) << 16);
}
#endif
// unpack a bf16 pair (one u32) to two floats: lo = bits<<16, hi = bits&0xffff0000
__device__ __forceinline__ f32x2 unpk(unsigned u) {
    return (f32x2){ __builtin_bit_cast(float, u << 16),
                    __builtin_bit_cast(float, u & 0xffff0000u) };
}
// exp2 direct (v_exp_f32 computes 2^x); fallback keeps old __expf path
#if __has_builtin(__builtin_amdgcn_exp2f)
#define EXP2F(x) __builtin_amdgcn_exp2f(x)
#else
#define EXP2F(x) __expf((x) * 0.6931471806f)
#endif
// tanh-form GELU, reciprocal formulation (|err| <~1e-3 vs exact):
//   gelu(x) = x / (1 + 2^(-y)),  y = log2e*2*0.79788456*(x + 0.044715 x^3)
// No clamp needed: 2^(-y)->inf => x/inf -> +-0 (correct tail);
//                  2^(-y)->0   => x     (correct tail). Denominator >= 1.
// negated pre-scaled constants: -0.10294793, -2.30220802
__device__ __forceinline__ float gelu_fast(float x) {
    float x2 = x * x;
    float ny = x * fmaf(x2, -0.10294793f, -2.30220802f);   // = -y
    float u  = EXP2F(ny);
    return x * __builtin_amdgcn_rcpf(1.0f + u);
}
// packed 2-element gelu: polynomial in v_pk_*, exp/rcp scalar (no pk transcendentals)
__device__ __forceinline__ f32x2 gelu2(f32x2 x) {
    f32x2 x2 = x * x;
    f32x2 ny = x * (x2 * -0.10294793f - 2.30220802f);      // = -y
    f32x2 d  = (f32x2){ EXP2F(ny.x), EXP2F(ny.y) } + 1.0f;
    return (f32x2){ x.x * __builtin_amdgcn_rcpf(d.x), x.y * __builtin_amdgcn_rcpf(d.y) };
}
__device__ __forceinline__ f32x2 shfl2(f32x2 v, int m) {
    return (f32x2){ __shfl_xor(v.x, m), __shfl_xor(v.y, m) };
}

// ---- DPP cross-lane (pure VALU, no DS pipe / lgkmcnt) ----
// 16-lane all-reduce via xor-levels {1,2,7,8}: a GF(2) basis of [0,16)
// (7 = 1^2^4 so 4 is in the span). All four exist as DPP ctrls:
//   xor1 = quad_perm[1,0,3,2] (0xB1), xor2 = quad_perm[2,3,0,1] (0x4E),
//   xor7 = row_half_mirror (0x141),   xor8 = row_ror:8 (0x128).
template<int CTRL>
__device__ __forceinline__ float dppf(float v) {
    int i = __builtin_bit_cast(int, v);
    return __builtin_bit_cast(float,
        __builtin_amdgcn_update_dpp(i, i, CTRL, 0xF, 0xF, false));
}
template<int CTRL>
__device__ __forceinline__ f32x2 dpp2(f32x2 v) {
    return (f32x2){ dppf<CTRL>(v.x), dppf<CTRL>(v.y) };
}
#define DPP_RED16(V) { V += dpp2<0xB1>(V); V += dpp2<0x4E>(V); \
                       V += dpp2<0x141>(V); V += dpp2<0x128>(V); }

__device__ __forceinline__ f32x4 mfma16(short8 a, short8 b, f32x4 c) {
    return __builtin_amdgcn_mfma_f32_16x16x32_bf16(a, b, c, 0, 0, 0);
}

// ===== single prep kernel, fully parallel =====
__global__ void prep_all(const float* __restrict__ w_embed, const float* __restrict__ b_embed,
                         const float* __restrict__ w1, const float* __restrict__ b1,
                         const float* __restrict__ w2,
                         unsigned short* __restrict__ wswM1, unsigned short* __restrict__ wsw2,
                         float* __restrict__ c1f) {
    int tid = blockIdx.x * 256 + threadIdx.x;          // 33280 total -> 130 blocks
    if (tid < 16384) {
        int oid = tid >> 2, sub = tid & 3;
        int j = oid & 7, lane = (oid >> 3) & 63, nt = (oid >> 9) & 7;
        int k = (lane >> 4) * 8 + j;
        int n = nt * 16 + (lane & 15);
        float acc = 0.f;
        if (k < IN_DIM) {
            #pragma unroll 8
            for (int c = sub * 32; c < sub * 32 + 32; ++c)
                acc = fmaf(w_embed[k*HID + c], w1[c*HID + n], acc);
        }
        acc += __shfl_xor(acc, 1);
        acc += __shfl_xor(acc, 2);
        if (sub == 0) wswM1[oid] = (k < IN_DIM) ? f2bf(acc) : (unsigned short)0;
    } else if (tid < 16896) {
        int t2 = tid - 16384;
        int n = t2 >> 2, sub = t2 & 3;
        float cb = 0.f;
        #pragma unroll 8
        for (int c = sub * 32; c < sub * 32 + 32; ++c)
            cb = fmaf(b_embed[c], w1[c*HID + n], cb);
        cb += __shfl_xor(cb, 1);
        cb += __shfl_xor(cb, 2);
        if (sub == 0) c1f[n] = 5.0f * cb + b1[n];
    } else if (tid < 33280) {
        int i2 = tid - 16896;
        int j = i2 & 7, lane = (i2 >> 3) & 63, nt = (i2 >> 9) & 7, ks = (i2 >> 12) & 3;
        int k = ks * 32 + (lane >> 4) * 8 + j;
        int n = nt * 16 + (lane & 15);
        wsw2[i2] = f2bf(w2[k*HID + n]);
    }
}

// ===== main =====
__global__ __launch_bounds__(128, 3) void hbond_main(
    const float* __restrict__ x_in,
    const float* __restrict__ c1f, const float* __restrict__ b2,
    const float* __restrict__ g1, const float* __restrict__ be1,
    const float* __restrict__ g2, const float* __restrict__ be2,
    const unsigned short* __restrict__ wswM1, const unsigned short* __restrict__ wsw2,
    float* __restrict__ out, int nItems)
{
    __shared__ __align__(16) unsigned char smem[IPB * SLICE];

    const int l  = threadIdx.x & 63;
    const int wv = threadIdx.x >> 6;
    const int item = blockIdx.x * IPB + wv;
    if (item >= nItems) return;               // wave-uniform; no cross-wave barriers

    unsigned char* slice = smem + wv * SLICE;
    float*          xs   = (float*)(slice);                    // phase A
    unsigned short* adjx = (unsigned short*)(slice + ADJX_OFF);// phase A
    unsigned short* hrm  = (unsigned short*)(slice);           // phase B (aliases A)
    unsigned short* tT   = (unsigned short*)(slice);           // phase C (aliases B)
    unsigned*       resid1 = (unsigned*)(slice + RES1_OFF);    // mt=1 residual
    float4*         pos4 = (float4*)(slice + RES1_OFF);        // KNN pos table (phase A)

    const int ln15 = l & 15, q = l >> 4;
    const float* xb = x_in + (size_t)item * (N_NODES * IN_DIM);

    // guard for tT col127/q3 overread (bytes 6144..6160)
    if (l == 0) *(u32x4*)(slice + HTSTR * HID * 2) = (u32x4){0,0,0,0};

    // ---- stage x: 180 floats ----
    if (l < 45) ((float4*)xs)[l] = ((const float4*)xb)[l];
    WB();

    // ---- KNN, 2-way cooperative: rows in lanes l&31 (dup in 32-51); each
    //      partner pair splits the 20 candidates 10/10. d2 bit-exact; local
    //      argmin strict-< (tie->lowest local j), cross-merge tie->group 0
    //      (lower indices) => identical result to global scan. ----
    const int r = l & 31;
    const int rsel = (r < N_NODES) ? r : 0;
    const float px = xs[rsel*IN_DIM+6], py = xs[rsel*IN_DIM+7], pz = xs[rsel*IN_DIM+8];
    if (l < N_NODES) pos4[l] = (float4){px, py, pz, 0.f};
    WB();

    unsigned nbrp = 0;                        // 5 x 5-bit neighbor indices
    {
        const int jbase = (l >> 5) * 10;      // my candidate window [jbase, jbase+10)
        float d2[10];
        #pragma unroll
        for (int jj = 0; jj < 10; ++jj) {
            const float4 p = pos4[jbase + jj];
            float dx = __fsub_rn(px, p.x);
            float dy = __fsub_rn(py, p.y);
            float dz = __fsub_rn(pz, p.z);
            d2[jj] = __fadd_rn(__fadd_rn(__fmul_rn(dx,dx), __fmul_rn(dy,dy)), __fmul_rn(dz,dz));
        }
        unsigned used = 0u;
        #pragma unroll
        for (int k = 0; k < K_NBR; ++k) {
            float mb = INFINITY; int mj = jbase;
            #pragma unroll
            for (int jj = 0; jj < 10; ++jj) {
                bool take = (!((used >> jj) & 1u)) && (d2[jj] < mb);
                mb = take ? d2[jj] : mb;
                mj = take ? jbase + jj : mj;
            }
            const float pb = __shfl_xor(mb, 32);
            const int   pj = __shfl_xor(mj, 32);
            const bool pwin = (pb < mb) || ((pb == mb) && (pj < mj));
            const int wj = pwin ? pj : mj;
            if (!pwin) used |= 1u << (mj - jbase);
            nbrp |= (unsigned)wj << (5*k);
        }
    }

    // ---- adjacency bitmask + bf16 A-fragments (k=q*8+j; bits >=20 always 0) ----
    unsigned amask = 0;
    #pragma unroll
    for (int j = 0; j < K_NBR; ++j) amask |= 1u << ((nbrp >> (5*j)) & 31);
    const unsigned am0 = (unsigned)__shfl((int)amask, ln15);
    const unsigned am1 = (unsigned)__shfl((int)amask, ln15 + 16);
    short8 adjf0, adjf1;
    #pragma unroll
    for (int j = 0; j < 8; ++j) {
        adjf0[j] = (short)(((am0 >> (q*8 + j)) & 1u) ? 0x3F80 : 0);
        adjf1[j] = (short)(((am1 >> (q*8 + j)) & 1u) ? 0x3F80 : 0);
    }

    // ---- agg1 on raw x (fp32 exact, packed sums) ----
    if (l < N_NODES) {
        f32x2 s01 = {0,0}, s23 = {0,0}, s45 = {0,0}, s67 = {0,0};
        float s8 = 0.f;
        #pragma unroll
        for (int j = 0; j < K_NBR; ++j) {
            const int b0 = ((nbrp >> (5*j)) & 31) * IN_DIM;
            s01 += (f32x2){xs[b0+0], xs[b0+1]};
            s23 += (f32x2){xs[b0+2], xs[b0+3]};
            s45 += (f32x2){xs[b0+4], xs[b0+5]};
            s67 += (f32x2){xs[b0+6], xs[b0+7]};
            s8  += xs[b0+8];
        }
        u32x4 p0 = { cvtpk(s01.x,s01.y), cvtpk(s23.x,s23.y), cvtpk(s45.x,s45.y), cvtpk(s67.x,s67.y) };
        u32x4 p1 = { cvtpk(s8,0.f), 0, 0, 0 };
        *(u32x4*)&adjx[l*16 + 0] = p0;
        *(u32x4*)&adjx[l*16 + 8] = p1;
    }
    WB();

    f32x4 acc[2][8];
    const int rlo = ln15, rhi = (ln15 + 16 > 19) ? 19 : ln15 + 16;  // clamp garbage rows

    // ---- GEMM1: y1 = adjx @ M1 + c1  (K=32, 16 MFMA; B zero for k>=9) ----
    {
        const short8 a0 = *(const short8*)&adjx[rlo*16 + (q & 1)*8];
        const short8 a1 = *(const short8*)&adjx[rhi*16 + (q & 1)*8];
        #pragma unroll
        for (int nt = 0; nt < 8; ++nt) {
            const float bv = c1f[ln15 + 16*nt];
            f32x4 c0 = (f32x4){bv, bv, bv, bv};
            const short8 bfr = *(const short8*)&wswM1[nt*512 + l*8];
            acc[0][nt] = mfma16(a0, bfr, c0);
            acc[1][nt] = mfma16(a1, bfr, c0);
        }
    }

    // ---- LN1 + GELU (packed f32x2) -> h as packed bf16-pair u32s ----
    unsigned hU01[2][8], hU23[2][8];   // [mt][nt]: rows (reg0,reg1) / (reg2,reg3)
    {
        float gva[8], bva[8];
        #pragma unroll
        for (int nt = 0; nt < 8; ++nt) { gva[nt] = g1[ln15+16*nt]; bva[nt] = be1[ln15+16*nt]; }
        #pragma unroll
        for (int mt = 0; mt < 2; ++mt) {
            f32x2 s01={0,0}, s23={0,0}, t01={0,0}, t23={0,0};
            #pragma unroll
            for (int nt = 0; nt < 8; ++nt) {
                f32x2 v01 = {acc[mt][nt][0], acc[mt][nt][1]};
                f32x2 v23 = {acc[mt][nt][2], acc[mt][nt][3]};
                s01 += v01; s23 += v23;
                t01 += v01*v01; t23 += v23*v23;
            }
            DPP_RED16(s01); DPP_RED16(s23);
            DPP_RED16(t01); DPP_RED16(t23);
            f32x2 mean01 = s01 * (1.f/HID), mean23 = s23 * (1.f/HID);
            f32x2 var01  = t01 * (1.f/HID) - mean01*mean01;
            f32x2 var23  = t23 * (1.f/HID) - mean23*mean23;
            f32x2 rstd01 = { rsqrtf(fmaxf(var01.x,0.f)+EPS), rsqrtf(fmaxf(var01.y,0.f)+EPS) };
            f32x2 rstd23 = { rsqrtf(fmaxf(var23.x,0.f)+EPS), rsqrtf(fmaxf(var23.y,0.f)+EPS) };
            #pragma unroll
            for (int nt = 0; nt < 8; ++nt) {
                f32x2 v01 = {acc[mt][nt][0], acc[mt][nt][1]};
                f32x2 v23 = {acc[mt][nt][2], acc[mt][nt][3]};
                f32x2 h01 = gelu2((v01 - mean01) * rstd01 * gva[nt] + bva[nt]);
                f32x2 h23 = gelu2((v23 - mean23) * rstd23 * gva[nt] + bva[nt]);
                hU01[mt][nt] = cvtpk(h01.x, h01.y);
                hU23[mt][nt] = cvtpk(h23.x, h23.y);
            }
        }
    }
    WB();   // adjx/xs dead; GEMM1 A-reads complete

    // ---- scatter h: hrm row-major (GEMM2' A); mt=0 residual stays in regs,
    //      mt=1 residual (rows 16-19, q==0 lanes) -> resid1 LDS, then regs die ----
    #pragma unroll
    for (int nt = 0; nt < 8; ++nt) {
        const int col = ln15 + 16*nt;
        const unsigned u01 = hU01[0][nt], u23 = hU23[0][nt];
        hrm[(q*4+0)*HRSTR + col] = (unsigned short)u01;
        hrm[(q*4+1)*HRSTR + col] = (unsigned short)(u01 >> 16);
        hrm[(q*4+2)*HRSTR + col] = (unsigned short)u23;
        hrm[(q*4+3)*HRSTR + col] = (unsigned short)(u23 >> 16);
        if (q == 0) {
            const unsigned v01 = hU01[1][nt], v23 = hU23[1][nt];
            hrm[16*HRSTR + col] = (unsigned short)v01;
            hrm[17*HRSTR + col] = (unsigned short)(v01 >> 16);
            hrm[18*HRSTR + col] = (unsigned short)v23;
            hrm[19*HRSTR + col] = (unsigned short)(v23 >> 16);
            *(u32x2*)&resid1[(nt*16 + ln15)*2] = (u32x2){v01, v23};
        }
    }
    WB();

    // ---- GEMM2': t = h @ W2  (K=128, 64 MFMA; garbage rows clamped) ----
    #pragma unroll
    for (int nt = 0; nt < 8; ++nt) { acc[0][nt] = (f32x4){0,0,0,0}; acc[1][nt] = acc[0][nt]; }
    #pragma unroll
    for (int ks = 0; ks < 4; ++ks) {
        const short8 a0 = *(const short8*)&hrm[rlo*HRSTR + ks*32 + q*8];
        const short8 a1 = *(const short8*)&hrm[rhi*HRSTR + ks*32 + q*8];
        #pragma unroll
        for (int nt = 0; nt < 8; ++nt) {
            const short8 bfr = *(const short8*)&wsw2[(ks*8 + nt)*512 + l*8];
            acc[0][nt] = mfma16(a0, bfr, acc[0][nt]);
            acc[1][nt] = mfma16(a1, bfr, acc[1][nt]);
        }
    }
    WB();   // all hrm reads complete; tT may overwrite

    // ---- store t transposed: tT[col][row] ----
    #pragma unroll
    for (int nt = 0; nt < 8; ++nt) {
        const int col = ln15 + 16*nt;
        u32x2 w0 = { cvtpk(acc[0][nt][0], acc[0][nt][1]), cvtpk(acc[0][nt][2], acc[0][nt][3]) };
        *(u32x2*)&tT[col*HTSTR + q*4] = w0;
        if (q == 0) {
            u32x2 w1v = { cvtpk(acc[1][nt][0], acc[1][nt][1]), cvtpk(acc[1][nt][2], acc[1][nt][3]) };
            *(u32x2*)&tT[col*HTSTR + 16] = w1v;
        }
    }
    // zero row-slots 20..23 (stale bytes can encode Inf/NaN; 0*Inf = NaN in MFMA)
    *(u32x2*)&tT[l*HTSTR + 20]        = (u32x2){0,0};
    *(u32x2*)&tT[(l + 64)*HTSTR + 20] = (u32x2){0,0};
    WB();

    // ---- y2 = adj @ t + b2  (16 MFMA; reuse acc) ----
    #pragma unroll
    for (int nt = 0; nt < 8; ++nt) {
        const float bv = b2[ln15 + 16*nt];
        f32x4 c0 = (f32x4){bv, bv, bv, bv};
        const short8 bfr = *(const short8*)&tT[(ln15 + 16*nt)*HTSTR + q*8];
        acc[0][nt] = mfma16(adjf0, bfr, c0);
        acc[1][nt] = mfma16(adjf1, bfr, c0);
    }

    // ---- LN2 stats (packed, DPP reduce) ----
    f32x2 mean01[2], mean23[2], rstd01[2], rstd23[2];
    #pragma unroll
    for (int mt = 0; mt < 2; ++mt) {
        f32x2 s01={0,0}, s23={0,0}, t01={0,0}, t23={0,0};
        #pragma unroll
        for (int nt = 0; nt < 8; ++nt) {
            f32x2 v01 = {acc[mt][nt][0], acc[mt][nt][1]};
            f32x2 v23 = {acc[mt][nt][2], acc[mt][nt][3]};
            s01 += v01; s23 += v23;
            t01 += v01*v01; t23 += v23*v23;
        }
        DPP_RED16(s01); DPP_RED16(s23);
        DPP_RED16(t01); DPP_RED16(t23);
        mean01[mt] = s01 * (1.f/HID); mean23[mt] = s23 * (1.f/HID);
        f32x2 v01 = t01 * (1.f/HID) - mean01[mt]*mean01[mt];
        f32x2 v23 = t23 * (1.f/HID) - mean23[mt]*mean23[mt];
        rstd01[mt] = (f32x2){ rsqrtf(fmaxf(v01.x,0.f)+EPS), rsqrtf(fmaxf(v01.y,0.f)+EPS) };
        rstd23[mt] = (f32x2){ rsqrtf(fmaxf(v23.x,0.f)+EPS), rsqrtf(fmaxf(v23.y,0.f)+EPS) };
    }

    // ---- fused LN2-apply + residual + minmax + gelu + store ----
    // gelu unimodal: max over rows = max(gelu(rmin), gelu(rmax))
    #pragma unroll
    for (int nt = 0; nt < 8; ++nt) {
        const int col = ln15 + 16*nt;
        const float gv = g2[col], bv = be2[col];
        f32x2 y01 = ((f32x2){acc[0][nt][0], acc[0][nt][1]} - mean01[0]) * rstd01[0] * gv + bv;
        f32x2 y23 = ((f32x2){acc[0][nt][2], acc[0][nt][3]} - mean23[0]) * rstd23[0] * gv + bv;
        f32x2 r01 = y01 + unpk(hU01[0][nt]);
        f32x2 r23 = y23 + unpk(hU23[0][nt]);
        float rmax = fmaxf(fmaxf(r01.x, r01.y), fmaxf(r23.x, r23.y));
        float rmin = fminf(fminf(r01.x, r01.y), fminf(r23.x, r23.y));
        if (q == 0) {
            f32x2 z01 = ((f32x2){acc[1][nt][0], acc[1][nt][1]} - mean01[1]) * rstd01[1] * gv + bv;
            f32x2 z23 = ((f32x2){acc[1][nt][2], acc[1][nt][3]} - mean23[1]) * rstd23[1] * gv + bv;
            const u32x2 hx = *(const u32x2*)&resid1[(nt*16 + ln15)*2];
            f32x2 w01 = z01 + unpk(hx.x);
            f32x2 w23 = z23 + unpk(hx.y);
            rmax = fmaxf(rmax, fmaxf(fmaxf(w01.x, w01.y), fmaxf(w23.x, w23.y)));
            rmin = fminf(rmin, fminf(fminf(w01.x, w01.y), fminf(w23.x, w23.y)));
        }
        rmax = fmaxf(rmax, __shfl_xor(rmax, 16)); rmin = fminf(rmin, __shfl_xor(rmin, 16));
        rmax = fmaxf(rmax, __shfl_xor(rmax, 32)); rmin = fminf(rmin, __shfl_xor(rmin, 32));
        const f32x2 gmm = gelu2((f32x2){rmin, rmax});
        const float m0 = fmaxf(gmm.x, gmm.y);
        if (l < 16) out[(size_t)item*HID + 16*nt + l] = m0;
    }
}

extern "C" void kernel_launch(void* const* d_in, const int* in_sizes, int n_in,
                              void* d_out, int out_size, void* d_ws, size_t ws_size,
                              hipStream_t stream) {
    (void)n_in; (void)out_size; (void)ws_size;
    const float* x       = (const float*)d_in[0];
    const float* w_embed = (const float*)d_in[1];
    const float* b_embed = (const float*)d_in[2];
    const float* w1      = (const float*)d_in[3];
    const float* b1      = (const float*)d_in[4];
    const float* w2      = (const float*)d_in[5];
    const float* b2      = (const float*)d_in[6];
    const float* g1      = (const float*)d_in[7];
    const float* be1     = (const float*)d_in[8];
    const float* g2      = (const float*)d_in[9];
    const float* be2     = (const float*)d_in[10];
    float* out = (float*)d_out;

    // ws layout: [c1f 512B][wswM1 8192B][wsw2 32768B]
    unsigned char* ws = (unsigned char*)d_ws;
    float* c1f            = (float*)(ws + 0);
    unsigned short* wswM1 = (unsigned short*)(ws + 512);
    unsigned short* wsw2  = (unsigned short*)(ws + 512 + 8192);

    const int nItems  = in_sizes[0] / (N_NODES * IN_DIM);
    const int nBlocks = (nItems + IPB - 1) / IPB;

    prep_all<<<dim3(130), dim3(256), 0, stream>>>(w_embed, b_embed, w1, b1, w2,
                                                  wswM1, wsw2, c1f);
    hbond_main<<<dim3(nBlocks), dim3(128), 0, stream>>>(
        x, c1f, b2, g1, be1, g2, be2, wswM1, wsw2, out, nItems);
}

// Round 10
// 269.770 us; speedup vs baseline: 1.4296x; 1.0011x over previous
//
#include <hip/hip_runtime.h>
#include <math.h>

#define N_NODES 20
#define IN_DIM  9
#define HID     128
#define K_NBR   5
#define EPS     1e-5f
#define IPB     2          // items (waves) per 128-thread block

// ---- per-item LDS slice (bytes), regions with disjoint lifetimes alias at 0 ----
// phase A: xs (180 f32 = 720B @0) + adjx (20x16 bf16 = 640B @736)
// phase B: hrm (20 rows x 136 bf16 = 5440B @0)   h row-major, A-operand for t=h@W2
// phase C: tT  (128 cols x 24 bf16 = 6144B @0)   t transposed, B-operand for adj@t
// guard  : 16B zeros @6144 (col127/q3 B-frag overread target; never clobbered)
// resid1 : mt=1 residual rows 16-19, [nt][ln15] u32x2 = 1024B @6160 (scatter->final)
//          (aliased during phase A by pos4: 20 x float4 KNN position table)
// mt=0 residual stays in REGISTERS (hU01/hU23). 64-AGPR dual-mt accumulator kept:
// natural unified usage ~148 regs -> 3 waves/SIMD ceiling (bound-4 spills, r2/r4).
// LESSONS: (r7) no hand-written v_mfma asm — hazard recognizer can't see it.
//          (r8) permlane16/32_swap builtins gave wrong-partner merges — only
//          shfl_xor / verified DPP idioms are trusted for cross-lane.
// Round 10: hbond_main IDENTICAL to round 9 (207us, passing). prep_all rewritten
// for coalescing + grid shape: the constant ~62us wall-minus-main gap across all
// rounds is prep_all (adjacent threads read w1 16KB apart; 130 blocks = half the
// CUs idle). New prep: n-in-low-bits -> 256B/wave coalesced w1/w2 reads.
#define ADJX_OFF  736
#define RES1_OFF  6160
#define SLICE     7184
#define HTSTR     24       // tT row-slots per col (multiple of 8 -> b128-aligned reads)
#define HRSTR     136      // hrm row stride (272B: 16B-mult, 4 mod 32 banks -> 2-way free)

typedef __attribute__((ext_vector_type(8))) short short8;   // 8 bf16 (4 VGPRs)
typedef __attribute__((ext_vector_type(4))) float f32x4;    // MFMA C/D frag
typedef __attribute__((ext_vector_type(2))) float f32x2;    // v_pk_*_f32 carrier
typedef __attribute__((ext_vector_type(2))) unsigned int u32x2;
typedef __attribute__((ext_vector_type(4))) unsigned int u32x4;

#define WB() __builtin_amdgcn_wave_barrier()

__device__ __forceinline__ unsigned short f2bf(float f) {
    unsigned u = __builtin_bit_cast(unsigned, f);
    u += 0x7fffu + ((u >> 16) & 1u);          // RNE
    return (unsigned short)(u >> 16);
}
#if __has_builtin(__builtin_amdgcn_cvt_pk_bf16_f32)
typedef __attribute__((ext_vector_type(2))) __bf16 bf16x2;
__device__ __forceinline__ unsigned cvtpk(float a, float b) {   // low=bf16(a), hi=bf16(b)
    bf16x2 r = __builtin_amdgcn_cvt_pk_bf16_f32(a, b);
    return __builtin_bit_cast(unsigned, r);
}
#else
__device__ __forceinline__ unsigned cvtpk(float a, float b) {
    return (unsigned)f2bf(a) | ((unsigned)f2bf(b) << 16);
}
#endif
// unpack a bf16 pair (one u32) to two floats: lo = bits<<16, hi = bits&0xffff0000
__device__ __forceinline__ f32x2 unpk(unsigned u) {
    return (f32x2){ __builtin_bit_cast(float, u << 16),
                    __builtin_bit_cast(float, u & 0xffff0000u) };
}
// exp2 direct (v_exp_f32 computes 2^x); fallback keeps old __expf path
#if __has_builtin(__builtin_amdgcn_exp2f)
#define EXP2F(x) __builtin_amdgcn_exp2f(x)
#else
#define EXP2F(x) __expf((x) * 0.6931471806f)
#endif
// tanh-form GELU, reciprocal formulation (|err| <~1e-3 vs exact):
//   gelu(x) = x / (1 + 2^(-y)),  y = log2e*2*0.79788456*(x + 0.044715 x^3)
// No clamp needed: 2^(-y)->inf => x/inf -> +-0 (correct tail);
//                  2^(-y)->0   => x     (correct tail). Denominator >= 1.
// negated pre-scaled constants: -0.10294793, -2.30220802
__device__ __forceinline__ float gelu_fast(float x) {
    float x2 = x * x;
    float ny = x * fmaf(x2, -0.10294793f, -2.30220802f);   // = -y
    float u  = EXP2F(ny);
    return x * __builtin_amdgcn_rcpf(1.0f + u);
}
// packed 2-element gelu: polynomial in v_pk_*, exp/rcp scalar (no pk transcendentals)
__device__ __forceinline__ f32x2 gelu2(f32x2 x) {
    f32x2 x2 = x * x;
    f32x2 ny = x * (x2 * -0.10294793f - 2.30220802f);      // = -y
    f32x2 d  = (f32x2){ EXP2F(ny.x), EXP2F(ny.y) } + 1.0f;
    return (f32x2){ x.x * __builtin_amdgcn_rcpf(d.x), x.y * __builtin_amdgcn_rcpf(d.y) };
}
__device__ __forceinline__ f32x2 shfl2(f32x2 v, int m) {
    return (f32x2){ __shfl_xor(v.x, m), __shfl_xor(v.y, m) };
}

// ---- DPP cross-lane (pure VALU, no DS pipe / lgkmcnt) ----
// 16-lane all-reduce via xor-levels {1,2,7,8}: a GF(2) basis of [0,16)
// (7 = 1^2^4 so 4 is in the span). All four exist as DPP ctrls:
//   xor1 = quad_perm[1,0,3,2] (0xB1), xor2 = quad_perm[2,3,0,1] (0x4E),
//   xor7 = row_half_mirror (0x141),   xor8 = row_ror:8 (0x128).
template<int CTRL>
__device__ __forceinline__ float dppf(float v) {
    int i = __builtin_bit_cast(int, v);
    return __builtin_bit_cast(float,
        __builtin_amdgcn_update_dpp(i, i, CTRL, 0xF, 0xF, false));
}
template<int CTRL>
__device__ __forceinline__ f32x2 dpp2(f32x2 v) {
    return (f32x2){ dppf<CTRL>(v.x), dppf<CTRL>(v.y) };
}
#define DPP_RED16(V) { V += dpp2<0xB1>(V); V += dpp2<0x4E>(V); \
                       V += dpp2<0x141>(V); V += dpp2<0x128>(V); }

__device__ __forceinline__ f32x4 mfma16(short8 a, short8 b, f32x4 c) {
    return __builtin_amdgcn_mfma_f32_16x16x32_bf16(a, b, c, 0, 0, 0);
}

// ===== prep kernel v2: coalesced =====
// blocks 0..9 : wswM1 rows k=2b,2b+1 (b<9 rows 0..8 real; b==9 unused slot) —
//               remapped: blocks 0..8 -> k rows 0..8 via w_embed, block 9 -> c1f
//               (b_embed row). n = t&127 fast dim -> w1 reads 256B/wave coalesced.
// blocks 10,11: zero-fill wswM1 fragment slots with k>=9.
// blocks 12..75: wsw2 pack, coalesced w2 reads, scattered 2B writes.
__global__ void prep_all(const float* __restrict__ w_embed, const float* __restrict__ b_embed,
                         const float* __restrict__ w1, const float* __restrict__ b1,
                         const float* __restrict__ w2,
                         unsigned short* __restrict__ wswM1, unsigned short* __restrict__ wsw2,
                         float* __restrict__ c1f) {
    const int b = blockIdx.x, t = threadIdx.x;
    if (b < 10) {
        __shared__ float red[256];
        const int n = t & 127;
        const int half = t >> 7;                   // K-half: c in [half*64, half*64+64)
        const float* arow = (b < 9) ? (w_embed + b * HID) : b_embed;
        float acc = 0.f;
        #pragma unroll 16
        for (int c = half * 64; c < half * 64 + 64; ++c)
            acc = fmaf(arow[c], w1[c * HID + n], acc);   // w1: coalesced across n
        red[t] = acc;
        __syncthreads();
        if (half == 0) {
            const float s = red[t] + red[t + 128];
            if (b < 9) {
                // fragment index: k=b -> j=b&7, lane=((b>>3)<<4)+(n&15), nt=n>>4
                const int lane = ((b >> 3) << 4) + (n & 15);
                wswM1[(b & 7) + 8 * lane + 512 * (n >> 4)] = f2bf(s);
            } else {
                c1f[n] = 5.0f * s + b1[n];
            }
        }
    } else if (b < 12) {
        // zero slots whose k = (lane>>4)*8+j >= 9 (disjoint from compute writes)
        for (int i = (b - 10) * 2048 + t; i < (b - 10) * 2048 + 2048; i += 256) {
            const int j = i & 7, lane = (i >> 3) & 63;
            if (((lane >> 4) << 3) + j >= 9) wswM1[i] = 0;
        }
    } else {
        // wsw2: i over 16384, coalesced read w2[row][col], scatter to frag layout
        const int i = (b - 12) * 256 + t;
        const int col = i & 127, row = i >> 7;
        const unsigned short v = f2bf(w2[row * HID + col]);
        const int ks = row >> 5, k5 = row & 31;
        const int lane = ((k5 >> 3) << 4) + (col & 15);
        wsw2[(k5 & 7) + 8 * lane + 512 * (col >> 4) + 4096 * ks] = v;
    }
}

// ===== main =====
__global__ __launch_bounds__(128, 3) void hbond_main(
    const float* __restrict__ x_in,
    const float* __restrict__ c1f, const float* __restrict__ b2,
    const float* __restrict__ g1, const float* __restrict__ be1,
    const float* __restrict__ g2, const float* __restrict__ be2,
    const unsigned short* __restrict__ wswM1, const unsigned short* __restrict__ wsw2,
    float* __restrict__ out, int nItems)
{
    __shared__ __align__(16) unsigned char smem[IPB * SLICE];

    const int l  = threadIdx.x & 63;
    const int wv = threadIdx.x >> 6;
    const int item = blockIdx.x * IPB + wv;
    if (item >= nItems) return;               // wave-uniform; no cross-wave barriers

    unsigned char* slice = smem + wv * SLICE;
    float*          xs   = (float*)(slice);                    // phase A
    unsigned short* adjx = (unsigned short*)(slice + ADJX_OFF);// phase A
    unsigned short* hrm  = (unsigned short*)(slice);           // phase B (aliases A)
    unsigned short* tT   = (unsigned short*)(slice);           // phase C (aliases B)
    unsigned*       resid1 = (unsigned*)(slice + RES1_OFF);    // mt=1 residual
    float4*         pos4 = (float4*)(slice + RES1_OFF);        // KNN pos table (phase A)

    const int ln15 = l & 15, q = l >> 4;
    const float* xb = x_in + (size_t)item * (N_NODES * IN_DIM);

    // guard for tT col127/q3 overread (bytes 6144..6160)
    if (l == 0) *(u32x4*)(slice + HTSTR * HID * 2) = (u32x4){0,0,0,0};

    // ---- stage x: 180 floats ----
    if (l < 45) ((float4*)xs)[l] = ((const float4*)xb)[l];
    WB();

    // ---- KNN, 2-way cooperative: rows in lanes l&31 (dup in 32-51); each
    //      partner pair splits the 20 candidates 10/10. d2 bit-exact; local
    //      argmin strict-< (tie->lowest local j), cross-merge tie->group 0
    //      (lower indices) => identical result to global scan. ----
    const int r = l & 31;
    const int rsel = (r < N_NODES) ? r : 0;
    const float px = xs[rsel*IN_DIM+6], py = xs[rsel*IN_DIM+7], pz = xs[rsel*IN_DIM+8];
    if (l < N_NODES) pos4[l] = (float4){px, py, pz, 0.f};
    WB();

    unsigned nbrp = 0;                        // 5 x 5-bit neighbor indices
    {
        const int jbase = (l >> 5) * 10;      // my candidate window [jbase, jbase+10)
        float d2[10];
        #pragma unroll
        for (int jj = 0; jj < 10; ++jj) {
            const float4 p = pos4[jbase + jj];
            float dx = __fsub_rn(px, p.x);
            float dy = __fsub_rn(py, p.y);
            float dz = __fsub_rn(pz, p.z);
            d2[jj] = __fadd_rn(__fadd_rn(__fmul_rn(dx,dx), __fmul_rn(dy,dy)), __fmul_rn(dz,dz));
        }
        unsigned used = 0u;
        #pragma unroll
        for (int k = 0; k < K_NBR; ++k) {
            float mb = INFINITY; int mj = jbase;
            #pragma unroll
            for (int jj = 0; jj < 10; ++jj) {
                bool take = (!((used >> jj) & 1u)) && (d2[jj] < mb);
                mb = take ? d2[jj] : mb;
                mj = take ? jbase + jj : mj;
            }
            const float pb = __shfl_xor(mb, 32);
            const int   pj = __shfl_xor(mj, 32);
            const bool pwin = (pb < mb) || ((pb == mb) && (pj < mj));
            const int wj = pwin ? pj : mj;
            if (!pwin) used |= 1u << (mj - jbase);
            nbrp |= (unsigned)wj << (5*k);
        }
    }

    // ---- adjacency bitmask + bf16 A-fragments (k=q*8+j; bits >=20 always 0) ----
    unsigned amask = 0;
    #pragma unroll
    for (int j = 0; j < K_NBR; ++j) amask |= 1u << ((nbrp >> (5*j)) & 31);
    const unsigned am0 = (unsigned)__shfl((int)amask, ln15);
    const unsigned am1 = (unsigned)__shfl((int)amask, ln15 + 16);
    short8 adjf0, adjf1;
    #pragma unroll
    for (int j = 0; j < 8; ++j) {
        adjf0[j] = (short)(((am0 >> (q*8 + j)) & 1u) ? 0x3F80 : 0);
        adjf1[j] = (short)(((am1 >> (q*8 + j)) & 1u) ? 0x3F80 : 0);
    }

    // ---- agg1 on raw x (fp32 exact, packed sums) ----
    if (l < N_NODES) {
        f32x2 s01 = {0,0}, s23 = {0,0}, s45 = {0,0}, s67 = {0,0};
        float s8 = 0.f;
        #pragma unroll
        for (int j = 0; j < K_NBR; ++j) {
            const int b0 = ((nbrp >> (5*j)) & 31) * IN_DIM;
            s01 += (f32x2){xs[b0+0], xs[b0+1]};
            s23 += (f32x2){xs[b0+2], xs[b0+3]};
            s45 += (f32x2){xs[b0+4], xs[b0+5]};
            s67 += (f32x2){xs[b0+6], xs[b0+7]};
            s8  += xs[b0+8];
        }
        u32x4 p0 = { cvtpk(s01.x,s01.y), cvtpk(s23.x,s23.y), cvtpk(s45.x,s45.y), cvtpk(s67.x,s67.y) };
        u32x4 p1 = { cvtpk(s8,0.f), 0, 0, 0 };
        *(u32x4*)&adjx[l*16 + 0] = p0;
        *(u32x4*)&adjx[l*16 + 8] = p1;
    }
    WB();

    f32x4 acc[2][8];
    const int rlo = ln15, rhi = (ln15 + 16 > 19) ? 19 : ln15 + 16;  // clamp garbage rows

    // ---- GEMM1: y1 = adjx @ M1 + c1  (K=32, 16 MFMA; B zero for k>=9) ----
    {
        const short8 a0 = *(const short8*)&adjx[rlo*16 + (q & 1)*8];
        const short8 a1 = *(const short8*)&adjx[rhi*16 + (q & 1)*8];
        #pragma unroll
        for (int nt = 0; nt < 8; ++nt) {
            const float bv = c1f[ln15 + 16*nt];
            f32x4 c0 = (f32x4){bv, bv, bv, bv};
            const short8 bfr = *(const short8*)&wswM1[nt*512 + l*8];
            acc[0][nt] = mfma16(a0, bfr, c0);
            acc[1][nt] = mfma16(a1, bfr, c0);
        }
    }

    // ---- LN1 + GELU (packed f32x2) -> h as packed bf16-pair u32s ----
    unsigned hU01[2][8], hU23[2][8];   // [mt][nt]: rows (reg0,reg1) / (reg2,reg3)
    {
        float gva[8], bva[8];
        #pragma unroll
        for (int nt = 0; nt < 8; ++nt) { gva[nt] = g1[ln15+16*nt]; bva[nt] = be1[ln15+16*nt]; }
        #pragma unroll
        for (int mt = 0; mt < 2; ++mt) {
            f32x2 s01={0,0}, s23={0,0}, t01={0,0}, t23={0,0};
            #pragma unroll
            for (int nt = 0; nt < 8; ++nt) {
                f32x2 v01 = {acc[mt][nt][0], acc[mt][nt][1]};
                f32x2 v23 = {acc[mt][nt][2], acc[mt][nt][3]};
                s01 += v01; s23 += v23;
                t01 += v01*v01; t23 += v23*v23;
            }
            DPP_RED16(s01); DPP_RED16(s23);
            DPP_RED16(t01); DPP_RED16(t23);
            f32x2 mean01 = s01 * (1.f/HID), mean23 = s23 * (1.f/HID);
            f32x2 var01  = t01 * (1.f/HID) - mean01*mean01;
            f32x2 var23  = t23 * (1.f/HID) - mean23*mean23;
            f32x2 rstd01 = { rsqrtf(fmaxf(var01.x,0.f)+EPS), rsqrtf(fmaxf(var01.y,0.f)+EPS) };
            f32x2 rstd23 = { rsqrtf(fmaxf(var23.x,0.f)+EPS), rsqrtf(fmaxf(var23.y,0.f)+EPS) };
            #pragma unroll
            for (int nt = 0; nt < 8; ++nt) {
                f32x2 v01 = {acc[mt][nt][0], acc[mt][nt][1]};
                f32x2 v23 = {acc[mt][nt][2], acc[mt][nt][3]};
                f32x2 h01 = gelu2((v01 - mean01) * rstd01 * gva[nt] + bva[nt]);
                f32x2 h23 = gelu2((v23 - mean23) * rstd23 * gva[nt] + bva[nt]);
                hU01[mt][nt] = cvtpk(h01.x, h01.y);
                hU23[mt][nt] = cvtpk(h23.x, h23.y);
            }
        }
    }
    WB();   // adjx/xs dead; GEMM1 A-reads complete

    // ---- scatter h: hrm row-major (GEMM2' A); mt=0 residual stays in regs,
    //      mt=1 residual (rows 16-19, q==0 lanes) -> resid1 LDS, then regs die ----
    #pragma unroll
    for (int nt = 0; nt < 8; ++nt) {
        const int col = ln15 + 16*nt;
        const unsigned u01 = hU01[0][nt], u23 = hU23[0][nt];
        hrm[(q*4+0)*HRSTR + col] = (unsigned short)u01;
        hrm[(q*4+1)*HRSTR + col] = (unsigned short)(u01 >> 16);
        hrm[(q*4+2)*HRSTR + col] = (unsigned short)u23;
        hrm[(q*4+3)*HRSTR + col] = (unsigned short)(u23 >> 16);
        if (q == 0) {
            const unsigned v01 = hU01[1][nt], v23 = hU23[1][nt];
            hrm[16*HRSTR + col] = (unsigned short)v01;
            hrm[17*HRSTR + col] = (unsigned short)(v01 >> 16);
            hrm[18*HRSTR + col] = (unsigned short)v23;
            hrm[19*HRSTR + col] = (unsigned short)(v23 >> 16);
            *(u32x2*)&resid1[(nt*16 + ln15)*2] = (u32x2){v01, v23};
        }
    }
    WB();

    // ---- GEMM2': t = h @ W2  (K=128, 64 MFMA; garbage rows clamped) ----
    #pragma unroll
    for (int nt = 0; nt < 8; ++nt) { acc[0][nt] = (f32x4){0,0,0,0}; acc[1][nt] = acc[0][nt]; }
    #pragma unroll
    for (int ks = 0; ks < 4; ++ks) {
        const short8 a0 = *(const short8*)&hrm[rlo*HRSTR + ks*32 + q*8];
        const short8 a1 = *(const short8*)&hrm[rhi*HRSTR + ks*32 + q*8];
        #pragma unroll
        for (int nt = 0; nt < 8; ++nt) {
            const short8 bfr = *(const short8*)&wsw2[(ks*8 + nt)*512 + l*8];
            acc[0][nt] = mfma16(a0, bfr, acc[0][nt]);
            acc[1][nt] = mfma16(a1, bfr, acc[1][nt]);
        }
    }
    WB();   // all hrm reads complete; tT may overwrite

    // ---- store t transposed: tT[col][row] ----
    #pragma unroll
    for (int nt = 0; nt < 8; ++nt) {
        const int col = ln15 + 16*nt;
        u32x2 w0 = { cvtpk(acc[0][nt][0], acc[0][nt][1]), cvtpk(acc[0][nt][2], acc[0][nt][3]) };
        *(u32x2*)&tT[col*HTSTR + q*4] = w0;
        if (q == 0) {
            u32x2 w1v = { cvtpk(acc[1][nt][0], acc[1][nt][1]), cvtpk(acc[1][nt][2], acc[1][nt][3]) };
            *(u32x2*)&tT[col*HTSTR + 16] = w1v;
        }
    }
    // zero row-slots 20..23 (stale bytes can encode Inf/NaN; 0*Inf = NaN in MFMA)
    *(u32x2*)&tT[l*HTSTR + 20]        = (u32x2){0,0};
    *(u32x2*)&tT[(l + 64)*HTSTR + 20] = (u32x2){0,0};
    WB();

    // ---- y2 = adj @ t + b2  (16 MFMA; reuse acc) ----
    #pragma unroll
    for (int nt = 0; nt < 8; ++nt) {
        const float bv = b2[ln15 + 16*nt];
        f32x4 c0 = (f32x4){bv, bv, bv, bv};
        const short8 bfr = *(const short8*)&tT[(ln15 + 16*nt)*HTSTR + q*8];
        acc[0][nt] = mfma16(adjf0, bfr, c0);
        acc[1][nt] = mfma16(adjf1, bfr, c0);
    }

    // ---- LN2 stats (packed, DPP reduce) ----
    f32x2 mean01[2], mean23[2], rstd01[2], rstd23[2];
    #pragma unroll
    for (int mt = 0; mt < 2; ++mt) {
        f32x2 s01={0,0}, s23={0,0}, t01={0,0}, t23={0,0};
        #pragma unroll
        for (int nt = 0; nt < 8; ++nt) {
            f32x2 v01 = {acc[mt][nt][0], acc[mt][nt][1]};
            f32x2 v23 = {acc[mt][nt][2], acc[mt][nt][3]};
            s01 += v01; s23 += v23;
            t01 += v01*v01; t23 += v23*v23;
        }
        DPP_RED16(s01); DPP_RED16(s23);
        DPP_RED16(t01); DPP_RED16(t23);
        mean01[mt] = s01 * (1.f/HID); mean23[mt] = s23 * (1.f/HID);
        f32x2 v01 = t01 * (1.f/HID) - mean01[mt]*mean01[mt];
        f32x2 v23 = t23 * (1.f/HID) - mean23[mt]*mean23[mt];
        rstd01[mt] = (f32x2){ rsqrtf(fmaxf(v01.x,0.f)+EPS), rsqrtf(fmaxf(v01.y,0.f)+EPS) };
        rstd23[mt] = (f32x2){ rsqrtf(fmaxf(v23.x,0.f)+EPS), rsqrtf(fmaxf(v23.y,0.f)+EPS) };
    }

    // ---- fused LN2-apply + residual + minmax + gelu + store ----
    // gelu unimodal: max over rows = max(gelu(rmin), gelu(rmax))
    #pragma unroll
    for (int nt = 0; nt < 8; ++nt) {
        const int col = ln15 + 16*nt;
        const float gv = g2[col], bv = be2[col];
        f32x2 y01 = ((f32x2){acc[0][nt][0], acc[0][nt][1]} - mean01[0]) * rstd01[0] * gv + bv;
        f32x2 y23 = ((f32x2){acc[0][nt][2], acc[0][nt][3]} - mean23[0]) * rstd23[0] * gv + bv;
        f32x2 r01 = y01 + unpk(hU01[0][nt]);
        f32x2 r23 = y23 + unpk(hU23[0][nt]);
        float rmax = fmaxf(fmaxf(r01.x, r01.y), fmaxf(r23.x, r23.y));
        float rmin = fminf(fminf(r01.x, r01.y), fminf(r23.x, r23.y));
        if (q == 0) {
            f32x2 z01 = ((f32x2){acc[1][nt][0], acc[1][nt][1]} - mean01[1]) * rstd01[1] * gv + bv;
            f32x2 z23 = ((f32x2){acc[1][nt][2], acc[1][nt][3]} - mean23[1]) * rstd23[1] * gv + bv;
            const u32x2 hx = *(const u32x2*)&resid1[(nt*16 + ln15)*2];
            f32x2 w01 = z01 + unpk(hx.x);
            f32x2 w23 = z23 + unpk(hx.y);
            rmax = fmaxf(rmax, fmaxf(fmaxf(w01.x, w01.y), fmaxf(w23.x, w23.y)));
            rmin = fminf(rmin, fminf(fminf(w01.x, w01.y), fminf(w23.x, w23.y)));
        }
        rmax = fmaxf(rmax, __shfl_xor(rmax, 16)); rmin = fminf(rmin, __shfl_xor(rmin, 16));
        rmax = fmaxf(rmax, __shfl_xor(rmax, 32)); rmin = fminf(rmin, __shfl_xor(rmin, 32));
        const f32x2 gmm = gelu2((f32x2){rmin, rmax});
        const float m0 = fmaxf(gmm.x, gmm.y);
        if (l < 16) out[(size_t)item*HID + 16*nt + l] = m0;
    }
}

extern "C" void kernel_launch(void* const* d_in, const int* in_sizes, int n_in,
                              void* d_out, int out_size, void* d_ws, size_t ws_size,
                              hipStream_t stream) {
    (void)n_in; (void)out_size; (void)ws_size;
    const float* x       = (const float*)d_in[0];
    const float* w_embed = (const float*)d_in[1];
    const float* b_embed = (const float*)d_in[2];
    const float* w1      = (const float*)d_in[3];
    const float* b1      = (const float*)d_in[4];
    const float* w2      = (const float*)d_in[5];
    const float* b2      = (const float*)d_in[6];
    const float* g1      = (const float*)d_in[7];
    const float* be1     = (const float*)d_in[8];
    const float* g2      = (const float*)d_in[9];
    const float* be2     = (const float*)d_in[10];
    float* out = (float*)d_out;

    // ws layout: [c1f 512B][wswM1 8192B][wsw2 32768B]
    unsigned char* ws = (unsigned char*)d_ws;
    float* c1f            = (float*)(ws + 0);
    unsigned short* wswM1 = (unsigned short*)(ws + 512);
    unsigned short* wsw2  = (unsigned short*)(ws + 512 + 8192);

    const int nItems  = in_sizes[0] / (N_NODES * IN_DIM);
    const int nBlocks = (nItems + IPB - 1) / IPB;

    prep_all<<<dim3(76), dim3(256), 0, stream>>>(w_embed, b_embed, w1, b1, w2,
                                                 wswM1, wsw2, c1f);
    hbond_main<<<dim3(nBlocks), dim3(128), 0, stream>>>(
        x, c1f, b2, g1, be1, g2, be2, wswM1, wsw2, out, nItems);
}

// Round 11
// 268.323 us; speedup vs baseline: 1.4373x; 1.0054x over previous
//
#include <hip/hip_runtime.h>
#include <math.h>

#define N_NODES 20
#define IN_DIM  9
#define HID     128
#define K_NBR   5
#define EPS     1e-5f
#define IPB     2          // items (waves) per 128-thread block

// ---- per-item LDS slice (bytes), regions with disjoint lifetimes alias at 0 ----
// phase A: xs (180 f32 = 720B @0) + adjx (20x16 bf16 = 640B @736)
// phase B: hrm (20 rows x 136 bf16 = 5440B @0)   h row-major, A-operand for t=h@W2
// phase C: tT  (128 cols x 24 bf16 = 6144B @0)   t transposed, B-operand for adj@t
// guard  : 16B zeros @6144 (col127/q3 B-frag overread target; never clobbered)
// resid1 : mt=1 residual rows 16-19, [nt][ln15] u32x2 = 1024B @6160 (scatter->final)
//          (aliased during phase A by pos4: 20 x float4 KNN position table)
// mt=0 residual stays in REGISTERS (hU01/hU23). 64-AGPR dual-mt accumulator kept:
// natural unified usage ~148 regs -> 3 waves/SIMD ceiling (bound-4 spills, r2/r4).
// LESSONS: (r7) no hand-written v_mfma asm — hazard recognizer can't see it.
//          (r8) permlane16/32_swap builtins gave wrong-partner merges — only
//          shfl_xor / verified DPP idioms are trusted for cross-lane.
//          (r10) wall-minus-main ~60us is harness reset overhead, not prep;
//          rocprof per-dispatch dur has ±14% session noise — trust wall only.
// Round 11: (1) KNN used-mask -> INF-disable (static-indexed cndmask);
//           (2) exact tie identity: group1 yields on ties (pb<=mb);
//           (3) LN apply refactored to fma(v,A,B) with A=rstd*g, B=b-mean*A.
#define ADJX_OFF  736
#define RES1_OFF  6160
#define SLICE     7184
#define HTSTR     24       // tT row-slots per col (multiple of 8 -> b128-aligned reads)
#define HRSTR     136      // hrm row stride (272B: 16B-mult, 4 mod 32 banks -> 2-way free)

typedef __attribute__((ext_vector_type(8))) short short8;   // 8 bf16 (4 VGPRs)
typedef __attribute__((ext_vector_type(4))) float f32x4;    // MFMA C/D frag
typedef __attribute__((ext_vector_type(2))) float f32x2;    // v_pk_*_f32 carrier
typedef __attribute__((ext_vector_type(2))) unsigned int u32x2;
typedef __attribute__((ext_vector_type(4))) unsigned int u32x4;

#define WB() __builtin_amdgcn_wave_barrier()

__device__ __forceinline__ unsigned short f2bf(float f) {
    unsigned u = __builtin_bit_cast(unsigned, f);
    u += 0x7fffu + ((u >> 16) & 1u);          // RNE
    return (unsigned short)(u >> 16);
}
#if __has_builtin(__builtin_amdgcn_cvt_pk_bf16_f32)
typedef __attribute__((ext_vector_type(2))) __bf16 bf16x2;
__device__ __forceinline__ unsigned cvtpk(float a, float b) {   // low=bf16(a), hi=bf16(b)
    bf16x2 r = __builtin_amdgcn_cvt_pk_bf16_f32(a, b);
    return __builtin_bit_cast(unsigned, r);
}
#else
__device__ __forceinline__ unsigned cvtpk(float a, float b) {
    return (unsigned)f2bf(a) | ((unsigned)f2bf(b) << 16);
}
#endif
// unpack a bf16 pair (one u32) to two floats: lo = bits<<16, hi = bits&0xffff0000
__device__ __forceinline__ f32x2 unpk(unsigned u) {
    return (f32x2){ __builtin_bit_cast(float, u << 16),
                    __builtin_bit_cast(float, u & 0xffff0000u) };
}
// exp2 direct (v_exp_f32 computes 2^x); fallback keeps old __expf path
#if __has_builtin(__builtin_amdgcn_exp2f)
#define EXP2F(x) __builtin_amdgcn_exp2f(x)
#else
#define EXP2F(x) __expf((x) * 0.6931471806f)
#endif
// tanh-form GELU, reciprocal formulation (|err| <~1e-3 vs exact):
//   gelu(x) = x / (1 + 2^(-y)),  y = log2e*2*0.79788456*(x + 0.044715 x^3)
// No clamp needed: 2^(-y)->inf => x/inf -> +-0 (correct tail);
//                  2^(-y)->0   => x     (correct tail). Denominator >= 1.
// negated pre-scaled constants: -0.10294793, -2.30220802
__device__ __forceinline__ float gelu_fast(float x) {
    float x2 = x * x;
    float ny = x * fmaf(x2, -0.10294793f, -2.30220802f);   // = -y
    float u  = EXP2F(ny);
    return x * __builtin_amdgcn_rcpf(1.0f + u);
}
// packed 2-element gelu: polynomial in v_pk_*, exp/rcp scalar (no pk transcendentals)
__device__ __forceinline__ f32x2 gelu2(f32x2 x) {
    f32x2 x2 = x * x;
    f32x2 ny = x * (x2 * -0.10294793f - 2.30220802f);      // = -y
    f32x2 d  = (f32x2){ EXP2F(ny.x), EXP2F(ny.y) } + 1.0f;
    return (f32x2){ x.x * __builtin_amdgcn_rcpf(d.x), x.y * __builtin_amdgcn_rcpf(d.y) };
}
__device__ __forceinline__ f32x2 shfl2(f32x2 v, int m) {
    return (f32x2){ __shfl_xor(v.x, m), __shfl_xor(v.y, m) };
}

// ---- DPP cross-lane (pure VALU, no DS pipe / lgkmcnt) ----
// 16-lane all-reduce via xor-levels {1,2,7,8}: a GF(2) basis of [0,16)
// (7 = 1^2^4 so 4 is in the span). All four exist as DPP ctrls:
//   xor1 = quad_perm[1,0,3,2] (0xB1), xor2 = quad_perm[2,3,0,1] (0x4E),
//   xor7 = row_half_mirror (0x141),   xor8 = row_ror:8 (0x128).
template<int CTRL>
__device__ __forceinline__ float dppf(float v) {
    int i = __builtin_bit_cast(int, v);
    return __builtin_bit_cast(float,
        __builtin_amdgcn_update_dpp(i, i, CTRL, 0xF, 0xF, false));
}
template<int CTRL>
__device__ __forceinline__ f32x2 dpp2(f32x2 v) {
    return (f32x2){ dppf<CTRL>(v.x), dppf<CTRL>(v.y) };
}
#define DPP_RED16(V) { V += dpp2<0xB1>(V); V += dpp2<0x4E>(V); \
                       V += dpp2<0x141>(V); V += dpp2<0x128>(V); }

__device__ __forceinline__ f32x4 mfma16(short8 a, short8 b, f32x4 c) {
    return __builtin_amdgcn_mfma_f32_16x16x32_bf16(a, b, c, 0, 0, 0);
}

// ===== prep kernel v2: coalesced =====
__global__ void prep_all(const float* __restrict__ w_embed, const float* __restrict__ b_embed,
                         const float* __restrict__ w1, const float* __restrict__ b1,
                         const float* __restrict__ w2,
                         unsigned short* __restrict__ wswM1, unsigned short* __restrict__ wsw2,
                         float* __restrict__ c1f) {
    const int b = blockIdx.x, t = threadIdx.x;
    if (b < 10) {
        __shared__ float red[256];
        const int n = t & 127;
        const int half = t >> 7;                   // K-half: c in [half*64, half*64+64)
        const float* arow = (b < 9) ? (w_embed + b * HID) : b_embed;
        float acc = 0.f;
        #pragma unroll 16
        for (int c = half * 64; c < half * 64 + 64; ++c)
            acc = fmaf(arow[c], w1[c * HID + n], acc);   // w1: coalesced across n
        red[t] = acc;
        __syncthreads();
        if (half == 0) {
            const float s = red[t] + red[t + 128];
            if (b < 9) {
                const int lane = ((b >> 3) << 4) + (n & 15);
                wswM1[(b & 7) + 8 * lane + 512 * (n >> 4)] = f2bf(s);
            } else {
                c1f[n] = 5.0f * s + b1[n];
            }
        }
    } else if (b < 12) {
        for (int i = (b - 10) * 2048 + t; i < (b - 10) * 2048 + 2048; i += 256) {
            const int j = i & 7, lane = (i >> 3) & 63;
            if (((lane >> 4) << 3) + j >= 9) wswM1[i] = 0;
        }
    } else {
        const int i = (b - 12) * 256 + t;
        const int col = i & 127, row = i >> 7;
        const unsigned short v = f2bf(w2[row * HID + col]);
        const int ks = row >> 5, k5 = row & 31;
        const int lane = ((k5 >> 3) << 4) + (col & 15);
        wsw2[(k5 & 7) + 8 * lane + 512 * (col >> 4) + 4096 * ks] = v;
    }
}

// ===== main =====
__global__ __launch_bounds__(128, 3) void hbond_main(
    const float* __restrict__ x_in,
    const float* __restrict__ c1f, const float* __restrict__ b2,
    const float* __restrict__ g1, const float* __restrict__ be1,
    const float* __restrict__ g2, const float* __restrict__ be2,
    const unsigned short* __restrict__ wswM1, const unsigned short* __restrict__ wsw2,
    float* __restrict__ out, int nItems)
{
    __shared__ __align__(16) unsigned char smem[IPB * SLICE];

    const int l  = threadIdx.x & 63;
    const int wv = threadIdx.x >> 6;
    const int item = blockIdx.x * IPB + wv;
    if (item >= nItems) return;               // wave-uniform; no cross-wave barriers

    unsigned char* slice = smem + wv * SLICE;
    float*          xs   = (float*)(slice);                    // phase A
    unsigned short* adjx = (unsigned short*)(slice + ADJX_OFF);// phase A
    unsigned short* hrm  = (unsigned short*)(slice);           // phase B (aliases A)
    unsigned short* tT   = (unsigned short*)(slice);           // phase C (aliases B)
    unsigned*       resid1 = (unsigned*)(slice + RES1_OFF);    // mt=1 residual
    float4*         pos4 = (float4*)(slice + RES1_OFF);        // KNN pos table (phase A)

    const int ln15 = l & 15, q = l >> 4;
    const float* xb = x_in + (size_t)item * (N_NODES * IN_DIM);

    // guard for tT col127/q3 overread (bytes 6144..6160)
    if (l == 0) *(u32x4*)(slice + HTSTR * HID * 2) = (u32x4){0,0,0,0};

    // ---- stage x: 180 floats ----
    if (l < 45) ((float4*)xs)[l] = ((const float4*)xb)[l];
    WB();

    // ---- KNN, 2-way cooperative: rows in lanes l&31 (dup in 32-51); each
    //      partner pair splits the 20 candidates 10/10. d2 bit-exact.
    //      Selection: strict-< ascending scan (tie->lowest local index);
    //      won candidates disabled via INF (static-indexed cndmask, no mask
    //      bookkeeping). Merge tie rule: group0 has strictly lower indices,
    //      so group1 lanes yield on ties: pwin = hi ? pb<=mb : pb<mb.
    //      Composition == original global strict-< scan exactly. ----
    const int r = l & 31;
    const int rsel = (r < N_NODES) ? r : 0;
    const float px = xs[rsel*IN_DIM+6], py = xs[rsel*IN_DIM+7], pz = xs[rsel*IN_DIM+8];
    if (l < N_NODES) pos4[l] = (float4){px, py, pz, 0.f};
    WB();

    unsigned nbrp = 0;                        // 5 x 5-bit neighbor indices
    {
        const int jbase = (l >> 5) * 10;      // my candidate window [jbase, jbase+10)
        const bool hi = (jbase != 0);         // group-1: partner holds lower indices
        float d2[10];
        #pragma unroll
        for (int jj = 0; jj < 10; ++jj) {
            const float4 p = pos4[jbase + jj];
            float dx = __fsub_rn(px, p.x);
            float dy = __fsub_rn(py, p.y);
            float dz = __fsub_rn(pz, p.z);
            d2[jj] = __fadd_rn(__fadd_rn(__fmul_rn(dx,dx), __fmul_rn(dy,dy)), __fmul_rn(dz,dz));
        }
        #pragma unroll
        for (int k = 0; k < K_NBR; ++k) {
            float mb = d2[0]; int ml = 0;
            #pragma unroll
            for (int jj = 1; jj < 10; ++jj) {
                bool take = d2[jj] < mb;
                mb = take ? d2[jj] : mb;
                ml = take ? jj : ml;
            }
            const float pb = __shfl_xor(mb, 32);
            const int   pj = __shfl_xor(ml + jbase, 32);
            const bool pwin = hi ? (pb <= mb) : (pb < mb);
            nbrp |= (unsigned)(pwin ? pj : (ml + jbase)) << (5*k);
            const int msel = pwin ? -1 : ml;  // disable own candidate iff it won
            #pragma unroll
            for (int jj = 0; jj < 10; ++jj)
                d2[jj] = (jj == msel) ? INFINITY : d2[jj];
        }
    }

    // ---- adjacency bitmask + bf16 A-fragments (k=q*8+j; bits >=20 always 0) ----
    unsigned amask = 0;
    #pragma unroll
    for (int j = 0; j < K_NBR; ++j) amask |= 1u << ((nbrp >> (5*j)) & 31);
    const unsigned am0 = (unsigned)__shfl((int)amask, ln15);
    const unsigned am1 = (unsigned)__shfl((int)amask, ln15 + 16);
    short8 adjf0, adjf1;
    #pragma unroll
    for (int j = 0; j < 8; ++j) {
        adjf0[j] = (short)(((am0 >> (q*8 + j)) & 1u) ? 0x3F80 : 0);
        adjf1[j] = (short)(((am1 >> (q*8 + j)) & 1u) ? 0x3F80 : 0);
    }

    // ---- agg1 on raw x (fp32 exact, packed sums) ----
    if (l < N_NODES) {
        f32x2 s01 = {0,0}, s23 = {0,0}, s45 = {0,0}, s67 = {0,0};
        float s8 = 0.f;
        #pragma unroll
        for (int j = 0; j < K_NBR; ++j) {
            const int b0 = ((nbrp >> (5*j)) & 31) * IN_DIM;
            s01 += (f32x2){xs[b0+0], xs[b0+1]};
            s23 += (f32x2){xs[b0+2], xs[b0+3]};
            s45 += (f32x2){xs[b0+4], xs[b0+5]};
            s67 += (f32x2){xs[b0+6], xs[b0+7]};
            s8  += xs[b0+8];
        }
        u32x4 p0 = { cvtpk(s01.x,s01.y), cvtpk(s23.x,s23.y), cvtpk(s45.x,s45.y), cvtpk(s67.x,s67.y) };
        u32x4 p1 = { cvtpk(s8,0.f), 0, 0, 0 };
        *(u32x4*)&adjx[l*16 + 0] = p0;
        *(u32x4*)&adjx[l*16 + 8] = p1;
    }
    WB();

    f32x4 acc[2][8];
    const int rlo = ln15, rhi = (ln15 + 16 > 19) ? 19 : ln15 + 16;  // clamp garbage rows

    // ---- GEMM1: y1 = adjx @ M1 + c1  (K=32, 16 MFMA; B zero for k>=9) ----
    {
        const short8 a0 = *(const short8*)&adjx[rlo*16 + (q & 1)*8];
        const short8 a1 = *(const short8*)&adjx[rhi*16 + (q & 1)*8];
        #pragma unroll
        for (int nt = 0; nt < 8; ++nt) {
            const float bv = c1f[ln15 + 16*nt];
            f32x4 c0 = (f32x4){bv, bv, bv, bv};
            const short8 bfr = *(const short8*)&wswM1[nt*512 + l*8];
            acc[0][nt] = mfma16(a0, bfr, c0);
            acc[1][nt] = mfma16(a1, bfr, c0);
        }
    }

    // ---- LN1 + GELU (packed f32x2) -> h as packed bf16-pair u32s ----
    unsigned hU01[2][8], hU23[2][8];   // [mt][nt]: rows (reg0,reg1) / (reg2,reg3)
    {
        float gva[8], bva[8];
        #pragma unroll
        for (int nt = 0; nt < 8; ++nt) { gva[nt] = g1[ln15+16*nt]; bva[nt] = be1[ln15+16*nt]; }
        #pragma unroll
        for (int mt = 0; mt < 2; ++mt) {
            f32x2 s01={0,0}, s23={0,0}, t01={0,0}, t23={0,0};
            #pragma unroll
            for (int nt = 0; nt < 8; ++nt) {
                f32x2 v01 = {acc[mt][nt][0], acc[mt][nt][1]};
                f32x2 v23 = {acc[mt][nt][2], acc[mt][nt][3]};
                s01 += v01; s23 += v23;
                t01 += v01*v01; t23 += v23*v23;
            }
            DPP_RED16(s01); DPP_RED16(s23);
            DPP_RED16(t01); DPP_RED16(t23);
            f32x2 mean01 = s01 * (1.f/HID), mean23 = s23 * (1.f/HID);
            f32x2 var01  = t01 * (1.f/HID) - mean01*mean01;
            f32x2 var23  = t23 * (1.f/HID) - mean23*mean23;
            f32x2 rstd01 = { rsqrtf(fmaxf(var01.x,0.f)+EPS), rsqrtf(fmaxf(var01.y,0.f)+EPS) };
            f32x2 rstd23 = { rsqrtf(fmaxf(var23.x,0.f)+EPS), rsqrtf(fmaxf(var23.y,0.f)+EPS) };
            #pragma unroll
            for (int nt = 0; nt < 8; ++nt) {
                const f32x2 A01 = rstd01 * gva[nt];
                const f32x2 B01 = bva[nt] - mean01 * A01;
                const f32x2 A23 = rstd23 * gva[nt];
                const f32x2 B23 = bva[nt] - mean23 * A23;
                f32x2 v01 = {acc[mt][nt][0], acc[mt][nt][1]};
                f32x2 v23 = {acc[mt][nt][2], acc[mt][nt][3]};
                f32x2 h01 = gelu2(v01 * A01 + B01);
                f32x2 h23 = gelu2(v23 * A23 + B23);
                hU01[mt][nt] = cvtpk(h01.x, h01.y);
                hU23[mt][nt] = cvtpk(h23.x, h23.y);
            }
        }
    }
    WB();   // adjx/xs dead; GEMM1 A-reads complete

    // ---- scatter h: hrm row-major (GEMM2' A); mt=0 residual stays in regs,
    //      mt=1 residual (rows 16-19, q==0 lanes) -> resid1 LDS, then regs die ----
    #pragma unroll
    for (int nt = 0; nt < 8; ++nt) {
        const int col = ln15 + 16*nt;
        const unsigned u01 = hU01[0][nt], u23 = hU23[0][nt];
        hrm[(q*4+0)*HRSTR + col] = (unsigned short)u01;
        hrm[(q*4+1)*HRSTR + col] = (unsigned short)(u01 >> 16);
        hrm[(q*4+2)*HRSTR + col] = (unsigned short)u23;
        hrm[(q*4+3)*HRSTR + col] = (unsigned short)(u23 >> 16);
        if (q == 0) {
            const unsigned v01 = hU01[1][nt], v23 = hU23[1][nt];
            hrm[16*HRSTR + col] = (unsigned short)v01;
            hrm[17*HRSTR + col] = (unsigned short)(v01 >> 16);
            hrm[18*HRSTR + col] = (unsigned short)v23;
            hrm[19*HRSTR + col] = (unsigned short)(v23 >> 16);
            *(u32x2*)&resid1[(nt*16 + ln15)*2] = (u32x2){v01, v23};
        }
    }
    WB();

    // ---- GEMM2': t = h @ W2  (K=128, 64 MFMA; garbage rows clamped) ----
    #pragma unroll
    for (int nt = 0; nt < 8; ++nt) { acc[0][nt] = (f32x4){0,0,0,0}; acc[1][nt] = acc[0][nt]; }
    #pragma unroll
    for (int ks = 0; ks < 4; ++ks) {
        const short8 a0 = *(const short8*)&hrm[rlo*HRSTR + ks*32 + q*8];
        const short8 a1 = *(const short8*)&hrm[rhi*HRSTR + ks*32 + q*8];
        #pragma unroll
        for (int nt = 0; nt < 8; ++nt) {
            const short8 bfr = *(const short8*)&wsw2[(ks*8 + nt)*512 + l*8];
            acc[0][nt] = mfma16(a0, bfr, acc[0][nt]);
            acc[1][nt] = mfma16(a1, bfr, acc[1][nt]);
        }
    }
    WB();   // all hrm reads complete; tT may overwrite

    // ---- store t transposed: tT[col][row] ----
    #pragma unroll
    for (int nt = 0; nt < 8; ++nt) {
        const int col = ln15 + 16*nt;
        u32x2 w0 = { cvtpk(acc[0][nt][0], acc[0][nt][1]), cvtpk(acc[0][nt][2], acc[0][nt][3]) };
        *(u32x2*)&tT[col*HTSTR + q*4] = w0;
        if (q == 0) {
            u32x2 w1v = { cvtpk(acc[1][nt][0], acc[1][nt][1]), cvtpk(acc[1][nt][2], acc[1][nt][3]) };
            *(u32x2*)&tT[col*HTSTR + 16] = w1v;
        }
    }
    // zero row-slots 20..23 (stale bytes can encode Inf/NaN; 0*Inf = NaN in MFMA)
    *(u32x2*)&tT[l*HTSTR + 20]        = (u32x2){0,0};
    *(u32x2*)&tT[(l + 64)*HTSTR + 20] = (u32x2){0,0};
    WB();

    // ---- y2 = adj @ t + b2  (16 MFMA; reuse acc) ----
    #pragma unroll
    for (int nt = 0; nt < 8; ++nt) {
        const float bv = b2[ln15 + 16*nt];
        f32x4 c0 = (f32x4){bv, bv, bv, bv};
        const short8 bfr = *(const short8*)&tT[(ln15 + 16*nt)*HTSTR + q*8];
        acc[0][nt] = mfma16(adjf0, bfr, c0);
        acc[1][nt] = mfma16(adjf1, bfr, c0);
    }

    // ---- LN2 stats (packed, DPP reduce) ----
    f32x2 mean01[2], mean23[2], rstd01[2], rstd23[2];
    #pragma unroll
    for (int mt = 0; mt < 2; ++mt) {
        f32x2 s01={0,0}, s23={0,0}, t01={0,0}, t23={0,0};
        #pragma unroll
        for (int nt = 0; nt < 8; ++nt) {
            f32x2 v01 = {acc[mt][nt][0], acc[mt][nt][1]};
            f32x2 v23 = {acc[mt][nt][2], acc[mt][nt][3]};
            s01 += v01; s23 += v23;
            t01 += v01*v01; t23 += v23*v23;
        }
        DPP_RED16(s01); DPP_RED16(s23);
        DPP_RED16(t01); DPP_RED16(t23);
        mean01[mt] = s01 * (1.f/HID); mean23[mt] = s23 * (1.f/HID);
        f32x2 v01 = t01 * (1.f/HID) - mean01[mt]*mean01[mt];
        f32x2 v23 = t23 * (1.f/HID) - mean23[mt]*mean23[mt];
        rstd01[mt] = (f32x2){ rsqrtf(fmaxf(v01.x,0.f)+EPS), rsqrtf(fmaxf(v01.y,0.f)+EPS) };
        rstd23[mt] = (f32x2){ rsqrtf(fmaxf(v23.x,0.f)+EPS), rsqrtf(fmaxf(v23.y,0.f)+EPS) };
    }

    // ---- fused LN2-apply + residual + minmax + gelu + store ----
    // gelu unimodal: max over rows = max(gelu(rmin), gelu(rmax))
    #pragma unroll
    for (int nt = 0; nt < 8; ++nt) {
        const int col = ln15 + 16*nt;
        const float gv = g2[col], bv = be2[col];
        const f32x2 A01 = rstd01[0] * gv;
        const f32x2 B01 = bv - mean01[0] * A01;
        const f32x2 A23 = rstd23[0] * gv;
        const f32x2 B23 = bv - mean23[0] * A23;
        f32x2 r01 = ((f32x2){acc[0][nt][0], acc[0][nt][1]}) * A01 + B01 + unpk(hU01[0][nt]);
        f32x2 r23 = ((f32x2){acc[0][nt][2], acc[0][nt][3]}) * A23 + B23 + unpk(hU23[0][nt]);
        float rmax = fmaxf(fmaxf(r01.x, r01.y), fmaxf(r23.x, r23.y));
        float rmin = fminf(fminf(r01.x, r01.y), fminf(r23.x, r23.y));
        if (q == 0) {
            const f32x2 C01 = rstd01[1] * gv;
            const f32x2 D01 = bv - mean01[1] * C01;
            const f32x2 C23 = rstd23[1] * gv;
            const f32x2 D23 = bv - mean23[1] * C23;
            const u32x2 hx = *(const u32x2*)&resid1[(nt*16 + ln15)*2];
            f32x2 w01 = ((f32x2){acc[1][nt][0], acc[1][nt][1]}) * C01 + D01 + unpk(hx.x);
            f32x2 w23 = ((f32x2){acc[1][nt][2], acc[1][nt][3]}) * C23 + D23 + unpk(hx.y);
            rmax = fmaxf(rmax, fmaxf(fmaxf(w01.x, w01.y), fmaxf(w23.x, w23.y)));
            rmin = fminf(rmin, fminf(fminf(w01.x, w01.y), fminf(w23.x, w23.y)));
        }
        rmax = fmaxf(rmax, __shfl_xor(rmax, 16)); rmin = fminf(rmin, __shfl_xor(rmin, 16));
        rmax = fmaxf(rmax, __shfl_xor(rmax, 32)); rmin = fminf(rmin, __shfl_xor(rmin, 32));
        const f32x2 gmm = gelu2((f32x2){rmin, rmax});
        const float m0 = fmaxf(gmm.x, gmm.y);
        if (l < 16) out[(size_t)item*HID + 16*nt + l] = m0;
    }
}

extern "C" void kernel_launch(void* const* d_in, const int* in_sizes, int n_in,
                              void* d_out, int out_size, void* d_ws, size_t ws_size,
                              hipStream_t stream) {
    (void)n_in; (void)out_size; (void)ws_size;
    const float* x       = (const float*)d_in[0];
    const float* w_embed = (const float*)d_in[1];
    const float* b_embed = (const float*)d_in[2];
    const float* w1      = (const float*)d_in[3];
    const float* b1      = (const float*)d_in[4];
    const float* w2      = (const float*)d_in[5];
    const float* b2      = (const float*)d_in[6];
    const float* g1      = (const float*)d_in[7];
    const float* be1     = (const float*)d_in[8];
    const float* g2      = (const float*)d_in[9];
    const float* be2     = (const float*)d_in[10];
    float* out = (float*)d_out;

    // ws layout: [c1f 512B][wswM1 8192B][wsw2 32768B]
    unsigned char* ws = (unsigned char*)d_ws;
    float* c1f            = (float*)(ws + 0);
    unsigned short* wswM1 = (unsigned short*)(ws + 512);
    unsigned short* wsw2  = (unsigned short*)(ws + 512 + 8192);

    const int nItems  = in_sizes[0] / (N_NODES * IN_DIM);
    const int nBlocks = (nItems + IPB - 1) / IPB;

    prep_all<<<dim3(76), dim3(256), 0, stream>>>(w_embed, b_embed, w1, b1, w2,
                                                 wswM1, wsw2, c1f);
    hbond_main<<<dim3(nBlocks), dim3(128), 0, stream>>>(
        x, c1f, b2, g1, be1, g2, be2, wswM1, wsw2, out, nItems);
}